// Round 8
// baseline (1519.079 us; speedup 1.0000x reference)
//
#include <hip/hip_runtime.h>
#include <hip/hip_bf16.h>

#define HIDDEN   512
#define TSTEPS   256
#define HORIZON  24
#define BTOT     1024
#define BBLK     16
#define NWG      (BTOT / BBLK)      // 64 workgroups
#define NTHR     512                // 8 waves, 4 m-tiles each
#define KK       16                 // K slices (512 / 32)

typedef __attribute__((ext_vector_type(8))) __bf16         bf16x8;
typedef __attribute__((ext_vector_type(4))) float          f32x4;
typedef __attribute__((ext_vector_type(8))) unsigned short ushort8;
typedef __attribute__((ext_vector_type(4))) unsigned short us4;
typedef __attribute__((ext_vector_type(4))) unsigned int   uint4v;

__device__ __forceinline__ unsigned short f2bf(float f) {
    unsigned int u = __float_as_uint(f);
    u += 0x7FFFu + ((u >> 16) & 1u);   // RNE
    return (unsigned short)(u >> 16);
}
__device__ __forceinline__ float bf2f(unsigned short s) {
    return __uint_as_float(((unsigned int)s) << 16);
}

// LDS-ordering-only barrier (no vmcnt drain): weight prefetch stays in flight.
__device__ __forceinline__ void lds_barrier() {
    asm volatile("s_waitcnt lgkmcnt(0)" ::: "memory");
    __builtin_amdgcn_s_barrier();
    asm volatile("" ::: "memory");
}

// Issue one slice for all 4 m-tile streams (4 x buffer_load_dwordx4),
// self-incrementing each stream's voffset (INCSTR is an inline literal).
#define LOADW4(d0, d1, d2, d3, INCSTR)                               \
    asm volatile("buffer_load_dwordx4 %0, %4, %8, 0 offen\n\t"       \
                 "buffer_load_dwordx4 %1, %5, %8, 0 offen\n\t"       \
                 "buffer_load_dwordx4 %2, %6, %8, 0 offen\n\t"       \
                 "buffer_load_dwordx4 %3, %7, %8, 0 offen\n\t"       \
                 "v_add_u32 %4, " INCSTR ", %4\n\t"                  \
                 "v_add_u32 %5, " INCSTR ", %5\n\t"                  \
                 "v_add_u32 %6, " INCSTR ", %6\n\t"                  \
                 "v_add_u32 %7, " INCSTR ", %7"                      \
                 : "=&v"(d0), "=&v"(d1), "=&v"(d2), "=&v"(d3),       \
                   "+v"(vo0), "+v"(vo1), "+v"(vo2), "+v"(vo3)        \
                 : "s"(srsrc))

// Counted wait, data-tied to the 4 fragments about to be consumed.
#define WAITW4(a, b, c, d, N) \
    asm volatile("s_waitcnt vmcnt(" #N ")" : "+v"(a), "+v"(b), "+v"(c), "+v"(d))

// Persistent-pipeline iteration: wait slot k (N=28 steady), 4 MFMAs off the
// 2-deep bf pipe, prefetch bf slice k+2, re-issue slot k with next slice.
#define ITERP(k, INCSTR, DOLD) {                                                \
    WAITW4(w0[(k) & 7], w1[(k) & 7], w2[(k) & 7], w3[(k) & 7], 28);             \
    bf16x8 bfc = bf[(k) & 1];                                                   \
    acc0 = __builtin_amdgcn_mfma_f32_16x16x32_bf16(w0[(k) & 7], bfc, acc0, 0, 0, 0); \
    acc1 = __builtin_amdgcn_mfma_f32_16x16x32_bf16(w1[(k) & 7], bfc, acc1, 0, 0, 0); \
    acc2 = __builtin_amdgcn_mfma_f32_16x16x32_bf16(w2[(k) & 7], bfc, acc2, 0, 0, 0); \
    acc3 = __builtin_amdgcn_mfma_f32_16x16x32_bf16(w3[(k) & 7], bfc, acc3, 0, 0, 0); \
    if (DOLD) bf[(k) & 1] = *(const bf16x8*)(hr + (((k) + 2) * 64 + lane) * 8); \
    LOADW4(w0[(k) & 7], w1[(k) & 7], w2[(k) & 7], w3[(k) & 7], INCSTR); }

// Drain iteration (last step only): counted wait, no re-issue.
#define ITERD(k, N, DOLD) {                                                     \
    WAITW4(w0[(k) & 7], w1[(k) & 7], w2[(k) & 7], w3[(k) & 7], N);              \
    bf16x8 bfc = bf[(k) & 1];                                                   \
    acc0 = __builtin_amdgcn_mfma_f32_16x16x32_bf16(w0[(k) & 7], bfc, acc0, 0, 0, 0); \
    acc1 = __builtin_amdgcn_mfma_f32_16x16x32_bf16(w1[(k) & 7], bfc, acc1, 0, 0, 0); \
    acc2 = __builtin_amdgcn_mfma_f32_16x16x32_bf16(w2[(k) & 7], bfc, acc2, 0, 0, 0); \
    acc3 = __builtin_amdgcn_mfma_f32_16x16x32_bf16(w3[(k) & 7], bfc, acc3, 0, 0, 0); \
    if (DOLD) bf[(k) & 1] = *(const bf16x8*)(hr + (((k) + 2) * 64 + lane) * 8); }

// Pack Wh (f32 [512][512], row j = out-col, inner k) into bf16 A-fragment
// order, m-tile-major: Wpk[(ntg*16 + kk)*64 + lane] holds 8 bf16 of
//   A[m = ntg*16 + (lane&15)][k = kk*32 + ((lane>>4)&3)*8 + j]
__global__ void pack_wh(const float* __restrict__ Wh, ushort8* __restrict__ Wpk) {
    int tid  = blockIdx.x * blockDim.x + threadIdx.x;   // 0..32767
    int lane = tid & 63;
    int kk   = (tid >> 6) & 15;
    int ntg  = tid >> 10;                                // global m-tile 0..31
    int col  = ntg * 16 + (lane & 15);                   // out-col
    int k0   = kk * 32 + ((lane >> 4) & 3) * 8;
    const float* src = Wh + col * HIDDEN + k0;
    ushort8 v;
#pragma unroll
    for (int j = 0; j < 8; ++j) v[j] = f2bf(src[j]);
    Wpk[(ntg * 16 + kk) * 64 + lane] = v;
}

__global__ __launch_bounds__(NTHR)
__attribute__((amdgpu_waves_per_eu(2, 2)))   // 2 waves/EU -> 256-VGPR tier, no spills
void rnn_main(
    const float* __restrict__ x,      // [1024][256]
    const float* __restrict__ Wx_w,   // [512]
    const float* __restrict__ Wx_b,   // [512]
    const float* __restrict__ Wh_b,   // [512]
    const float* __restrict__ fc_w,   // [24][512]
    const float* __restrict__ fc_b,   // [24]
    const ushort8* __restrict__ Wpk,  // packed bf16 A-fragments (512 KB)
    float* __restrict__ out)          // [1024][24]
{
    // h in B-fragment-major layout: hfrag[buf][(kk*64 + lane)*8 ushorts]
    __shared__ __align__(16) unsigned short hfrag[2][KK * 64 * 8];  // 2 x 16 KB
    __shared__ float xs[TSTEPS][BBLK];                               // 16 KB

    const int tid  = threadIdx.x;
    const int lane = tid & 63;
    const int wave = tid >> 6;       // 0..7, owns m-tiles 4w .. 4w+3
    const int bb   = blockIdx.x * BBLK;
    const int arow = lane & 15;      // C/D col = batch row
    const int rowg = lane >> 4;

    // stage x transposed: xs[t][r]
    for (int i = tid; i < BBLK * TSTEPS; i += NTHR) {
        int t = i & 255, r = i >> 8;
        xs[t][r] = x[(bb + r) * TSTEPS + t];
    }
    // h0 = 0
    {
        uint4v z = {0u, 0u, 0u, 0u};
        uint4v* p = (uint4v*)hfrag[0];
        p[tid] = z; p[tid + NTHR] = z;
    }

    // SRSRC descriptor over the 512 KB packed-weight buffer
    uint4v srsrc;
    {
        unsigned long long b = (unsigned long long)Wpk;
        srsrc[0] = (unsigned int)b;
        srsrc[1] = (unsigned int)(b >> 32);   // stride=0
        srsrc[2] = 512 * 1024;                // num_records (bytes)
        srsrc[3] = 0x00020000;                // raw dword access
    }
    // per-stream voffset, slice 0: byte = (tile*1024 + lane)*16
    unsigned int vo0 = ((wave * 4 + 0) * 1024 + lane) * 16;
    unsigned int vo1 = ((wave * 4 + 1) * 1024 + lane) * 16;
    unsigned int vo2 = ((wave * 4 + 2) * 1024 + lane) * 16;
    unsigned int vo3 = ((wave * 4 + 3) * 1024 + lane) * 16;

    // per-lane step-invariant init constants: out-col = wave*64+mt*16+rowg*4+r
    f32x4 wxw_c[4], bias_c[4];
#pragma unroll
    for (int mt = 0; mt < 4; ++mt) {
#pragma unroll
        for (int r = 0; r < 4; ++r) {
            int oc = wave * 64 + mt * 16 + rowg * 4 + r;
            wxw_c[mt][r]  = Wx_w[oc];
            bias_c[mt][r] = Wx_b[oc] + Wh_b[oc];
        }
    }

    __syncthreads();   // full drain; no compiler-tracked VMEM outstanding past here

    // ---- persistent prologue: issue slices 0..7 for all 4 streams (32 loads
    //      in flight; the pipeline never drains until the peeled last step) ----
    bf16x8 w0[8], w1[8], w2[8], w3[8];
    LOADW4(w0[0], w1[0], w2[0], w3[0], "0x400");
    LOADW4(w0[1], w1[1], w2[1], w3[1], "0x400");
    LOADW4(w0[2], w1[2], w2[2], w3[2], "0x400");
    LOADW4(w0[3], w1[3], w2[3], w3[3], "0x400");
    LOADW4(w0[4], w1[4], w2[4], w3[4], "0x400");
    LOADW4(w0[5], w1[5], w2[5], w3[5], "0x400");
    LOADW4(w0[6], w1[6], w2[6], w3[6], "0x400");
    LOADW4(w0[7], w1[7], w2[7], w3[7], "0x400");   // voff now at slice 8

#pragma clang loop unroll(disable)
    for (int t = 0; t < TSTEPS - 1; ++t) {
        const unsigned short* hr = hfrag[t & 1];
        unsigned short*       hw = hfrag[(t + 1) & 1];

        // 2-deep bf pipeline prologue + acc init (overlaps bf0/bf1 latency)
        bf16x8 bf[2];
        bf[0] = *(const bf16x8*)(hr + (0 * 64 + lane) * 8);
        bf[1] = *(const bf16x8*)(hr + (1 * 64 + lane) * 8);
        const float xv = xs[t][arow];
        f32x4 acc0, acc1, acc2, acc3;
#pragma unroll
        for (int r = 0; r < 4; ++r) {
            acc0[r] = xv * wxw_c[0][r] + bias_c[0][r];
            acc1[r] = xv * wxw_c[1][r] + bias_c[1][r];
            acc2[r] = xv * wxw_c[2][r] + bias_c[2][r];
            acc3[r] = xv * wxw_c[3][r] + bias_c[3][r];
        }

        // iters 0..7 issue slices 8..15 (this step), iter 7 wraps voff;
        // iters 8..15 issue slices 0..7 (NEXT step) — mature across barrier.
        ITERP(0,  "0x400", 1);
        ITERP(1,  "0x400", 1);
        ITERP(2,  "0x400", 1);
        ITERP(3,  "0x400", 1);
        ITERP(4,  "0x400", 1);
        ITERP(5,  "0x400", 1);
        ITERP(6,  "0x400", 1);
        ITERP(7,  "0xffffc400", 1);   // wrap -15360: back to slice 0
        ITERP(8,  "0x400", 1);
        ITERP(9,  "0x400", 1);
        ITERP(10, "0x400", 1);
        ITERP(11, "0x400", 1);
        ITERP(12, "0x400", 1);
        ITERP(13, "0x400", 1);
        ITERP(14, "0x400", 0);
        ITERP(15, "0x400", 0);        // voff back at slice 8 for next step

        // epilogue: tanh + frag-major h write (mapping verified rounds 3-4):
        // slice kkp = wave*2 + (mt>>1), chunk = (mt*2+(rowg>>1))&3, j0=(rowg&1)*4
        {
            f32x4 accs[4] = {acc0, acc1, acc2, acc3};
#pragma unroll
            for (int mt = 0; mt < 4; ++mt) {
                us4 pk;
#pragma unroll
                for (int r = 0; r < 4; ++r) {
                    float v = accs[mt][r];
                    float e = __expf(2.0f * v);
                    pk[r] = f2bf(1.0f - 2.0f / (e + 1.0f));
                }
                int kkp   = wave * 2 + (mt >> 1);
                int chunk = (mt * 2 + (rowg >> 1)) & 3;
                int j0    = (rowg & 1) * 4;
                *(us4*)(hw + (kkp * 64 + chunk * 16 + arow) * 8 + j0) = pk;
            }
        }
        lds_barrier();
    }

    // ---- peeled last step (t = TSTEPS-1): drain, vmcnt ends at 0 ----
    {
        const int t = TSTEPS - 1;
        const unsigned short* hr = hfrag[t & 1];
        unsigned short*       hw = hfrag[0];

        bf16x8 bf[2];
        bf[0] = *(const bf16x8*)(hr + (0 * 64 + lane) * 8);
        bf[1] = *(const bf16x8*)(hr + (1 * 64 + lane) * 8);
        const float xv = xs[t][arow];
        f32x4 acc0, acc1, acc2, acc3;
#pragma unroll
        for (int r = 0; r < 4; ++r) {
            acc0[r] = xv * wxw_c[0][r] + bias_c[0][r];
            acc1[r] = xv * wxw_c[1][r] + bias_c[1][r];
            acc2[r] = xv * wxw_c[2][r] + bias_c[2][r];
            acc3[r] = xv * wxw_c[3][r] + bias_c[3][r];
        }
        // iters 0..7 still must issue slices 8..15 for THIS step
        ITERP(0, "0x400", 1);
        ITERP(1, "0x400", 1);
        ITERP(2, "0x400", 1);
        ITERP(3, "0x400", 1);
        ITERP(4, "0x400", 1);
        ITERP(5, "0x400", 1);
        ITERP(6, "0x400", 1);
        ITERP(7, "0x400", 1);
        // iters 8..15: consume without re-issue; counted drain to 0
        ITERD(8,  28, 1);
        ITERD(9,  24, 1);
        ITERD(10, 20, 1);
        ITERD(11, 16, 1);
        ITERD(12, 12, 1);
        ITERD(13, 8,  1);
        ITERD(14, 4,  0);
        ITERD(15, 0,  0);

        {
            f32x4 accs[4] = {acc0, acc1, acc2, acc3};
#pragma unroll
            for (int mt = 0; mt < 4; ++mt) {
                us4 pk;
#pragma unroll
                for (int r = 0; r < 4; ++r) {
                    float v = accs[mt][r];
                    float e = __expf(2.0f * v);
                    pk[r] = f2bf(1.0f - 2.0f / (e + 1.0f));
                }
                int kkp   = wave * 2 + (mt >> 1);
                int chunk = (mt * 2 + (rowg >> 1)) & 3;
                int j0    = (rowg & 1) * 4;
                *(us4*)(hw + (kkp * 64 + chunk * 16 + arow) * 8 + j0) = pk;
            }
        }
        lds_barrier();
    }

    // final h is in hfrag[0]. fc head: 16 x 24 outputs.
    if (tid < BBLK * HORIZON) {
        int row = tid / HORIZON;
        int ho  = tid - row * HORIZON;
        float acc = fc_b[ho];
        const float* fw = fc_w + ho * HIDDEN;
        const unsigned short* hf = hfrag[0];
#pragma unroll 4
        for (int kk = 0; kk < KK; ++kk) {
#pragma unroll
            for (int c = 0; c < 4; ++c) {
                ushort8 hv = *(const ushort8*)(hf + (kk * 64 + c * 16 + row) * 8);
#pragma unroll
                for (int j = 0; j < 8; ++j)
                    acc += bf2f(hv[j]) * fw[kk * 32 + c * 8 + j];
            }
        }
        out[(bb + row) * HORIZON + ho] = acc;
    }
}

extern "C" void kernel_launch(void* const* d_in, const int* in_sizes, int n_in,
                              void* d_out, int out_size, void* d_ws, size_t ws_size,
                              hipStream_t stream) {
    const float* x    = (const float*)d_in[0];
    const float* Wx_w = (const float*)d_in[1];
    const float* Wx_b = (const float*)d_in[2];
    const float* Wh_w = (const float*)d_in[3];
    const float* Wh_b = (const float*)d_in[4];
    const float* fc_w = (const float*)d_in[5];
    const float* fc_b = (const float*)d_in[6];
    float* out = (float*)d_out;

    ushort8* Wpk = (ushort8*)d_ws;   // 512 KB packed weights

    hipLaunchKernelGGL(pack_wh, dim3(128), dim3(256), 0, stream, Wh_w, Wpk);
    hipLaunchKernelGGL(rnn_main, dim3(NWG), dim3(NTHR), 0, stream,
                       x, Wx_w, Wx_b, Wh_b, fc_w, fc_b,
                       (const ushort8*)Wpk, out);
}

// Round 9
// 721.148 us; speedup vs baseline: 2.1065x; 2.1065x over previous
//
#include <hip/hip_runtime.h>
#include <hip/hip_bf16.h>

#define HIDDEN   512
#define TSTEPS   256
#define HORIZON  24
#define BTOT     1024
#define BBLK     16
#define NWG      (BTOT / BBLK)      // 64 workgroups
#define NTHR     512                // 8 waves, 4 m-tiles each
#define NKK      8                  // K slices (512 / 64)

typedef __attribute__((ext_vector_type(4))) int            i32x4;
typedef __attribute__((ext_vector_type(4))) float          f32x4;
typedef __attribute__((ext_vector_type(8))) unsigned short ushort8;
typedef __attribute__((ext_vector_type(4))) unsigned short us4;
typedef __attribute__((ext_vector_type(4))) unsigned int   uint4v;

__device__ __forceinline__ unsigned short f2bf(float f) {
    unsigned int u = __float_as_uint(f);
    u += 0x7FFFu + ((u >> 16) & 1u);   // RNE
    return (unsigned short)(u >> 16);
}
__device__ __forceinline__ float bf2f(unsigned short s) {
    return __uint_as_float(((unsigned int)s) << 16);
}

// LDS-ordering-only barrier (no vmcnt drain): weight stream stays in flight.
__device__ __forceinline__ void lds_barrier() {
    asm volatile("s_waitcnt lgkmcnt(0)" ::: "memory");
    __builtin_amdgcn_s_barrier();
    asm volatile("" ::: "memory");
}

// Issue one k-slice for all 4 m-tile streams; self-incrementing voffsets.
#define LOADW4(d0, d1, d2, d3, INCSTR)                               \
    asm volatile("buffer_load_dwordx4 %0, %4, %8, 0 offen\n\t"       \
                 "buffer_load_dwordx4 %1, %5, %8, 0 offen\n\t"       \
                 "buffer_load_dwordx4 %2, %6, %8, 0 offen\n\t"       \
                 "buffer_load_dwordx4 %3, %7, %8, 0 offen\n\t"       \
                 "v_add_u32 %4, " INCSTR ", %4\n\t"                  \
                 "v_add_u32 %5, " INCSTR ", %5\n\t"                  \
                 "v_add_u32 %6, " INCSTR ", %6\n\t"                  \
                 "v_add_u32 %7, " INCSTR ", %7"                      \
                 : "=&v"(d0), "=&v"(d1), "=&v"(d2), "=&v"(d3),       \
                   "+v"(vo0), "+v"(vo1), "+v"(vo2), "+v"(vo3)        \
                 : "s"(srsrc))

#define WAIT4(a, b, c, d, N) \
    asm volatile("s_waitcnt vmcnt(" #N ")" : "+v"(a), "+v"(b), "+v"(c), "+v"(d))

// Persistent-pipeline iteration: wait slot (12 = 16 in flight minus oldest 4),
// 4 i8-MFMAs, prefetch h-frag 2 ahead, re-issue slot with next slice.
#define ITERP(k, INCSTR, DOLD) {                                                \
    WAIT4(s0[(k) & 3], s1[(k) & 3], s2[(k) & 3], s3[(k) & 3], 12);              \
    i32x4 bfc = bf[(k) & 1];                                                    \
    acc0 = __builtin_amdgcn_mfma_i32_16x16x64_i8(s0[(k) & 3], bfc, acc0, 0, 0, 0); \
    acc1 = __builtin_amdgcn_mfma_i32_16x16x64_i8(s1[(k) & 3], bfc, acc1, 0, 0, 0); \
    acc2 = __builtin_amdgcn_mfma_i32_16x16x64_i8(s2[(k) & 3], bfc, acc2, 0, 0, 0); \
    acc3 = __builtin_amdgcn_mfma_i32_16x16x64_i8(s3[(k) & 3], bfc, acc3, 0, 0, 0); \
    if (DOLD) bf[(k) & 1] = *(const i32x4*)(hr + ((k) + 2) * 1024 + lane * 16); \
    LOADW4(s0[(k) & 3], s1[(k) & 3], s2[(k) & 3], s3[(k) & 3], INCSTR); }

// Drain iteration (last step): counted wait, no re-issue.
#define ITERD(k, N, DOLD) {                                                     \
    WAIT4(s0[(k) & 3], s1[(k) & 3], s2[(k) & 3], s3[(k) & 3], N);               \
    i32x4 bfc = bf[(k) & 1];                                                    \
    acc0 = __builtin_amdgcn_mfma_i32_16x16x64_i8(s0[(k) & 3], bfc, acc0, 0, 0, 0); \
    acc1 = __builtin_amdgcn_mfma_i32_16x16x64_i8(s1[(k) & 3], bfc, acc1, 0, 0, 0); \
    acc2 = __builtin_amdgcn_mfma_i32_16x16x64_i8(s2[(k) & 3], bfc, acc2, 0, 0, 0); \
    acc3 = __builtin_amdgcn_mfma_i32_16x16x64_i8(s3[(k) & 3], bfc, acc3, 0, 0, 0); \
    if (DOLD) bf[(k) & 1] = *(const i32x4*)(hr + ((k) + 2) * 1024 + lane * 16); }

// ---- prep 1: per-out-col scales. 1 wave per oc. ----
__global__ void pack_scales(const float* __restrict__ Wh,
                            float* __restrict__ invq,    // 127/max
                            float* __restrict__ sclq) {  // max/(127*127)
    int oc   = blockIdx.x;
    int lane = threadIdx.x;
    float m = 0.f;
#pragma unroll
    for (int j = 0; j < 8; ++j) m = fmaxf(m, fabsf(Wh[oc * HIDDEN + lane * 8 + j]));
    for (int d = 1; d < 64; d <<= 1) m = fmaxf(m, __shfl_xor(m, d));
    if (lane == 0) {
        float inv = (m > 0.f) ? 127.0f / m : 0.f;
        invq[oc] = inv;
        sclq[oc] = m / (127.0f * 127.0f);
    }
}

// ---- prep 2: quantize + pack into i8 A-fragment order.
// Frag (tile, kk, lane) holds 16 int8 of A[oc=tile*16+(lane&15)][k=kk*64+(lane>>4)*16+j]
__global__ void pack_q(const float* __restrict__ Wh,
                       const float* __restrict__ invq,
                       i32x4* __restrict__ Wpk8) {
    int tid  = blockIdx.x * blockDim.x + threadIdx.x;   // 0..16383
    int lane = tid & 63;
    int kk   = (tid >> 6) & 7;
    int mt   = tid >> 9;                                 // global tile 0..31
    int oc   = mt * 16 + (lane & 15);
    int k0   = kk * 64 + (lane >> 4) * 16;
    float inv = invq[oc];
    const float* src = Wh + oc * HIDDEN + k0;
    int w[4];
#pragma unroll
    for (int d = 0; d < 4; ++d) {
        int b0 = __float2int_rn(src[d * 4 + 0] * inv) & 255;
        int b1 = __float2int_rn(src[d * 4 + 1] * inv) & 255;
        int b2 = __float2int_rn(src[d * 4 + 2] * inv) & 255;
        int b3 = __float2int_rn(src[d * 4 + 3] * inv) & 255;
        w[d] = b0 | (b1 << 8) | (b2 << 16) | (b3 << 24);
    }
    i32x4 v = {w[0], w[1], w[2], w[3]};
    Wpk8[(mt * 8 + kk) * 64 + lane] = v;
}

__global__ __launch_bounds__(NTHR) void rnn_main(
    const float* __restrict__ x,      // [1024][256]
    const float* __restrict__ Wx_w,   // [512]
    const float* __restrict__ Wx_b,   // [512]
    const float* __restrict__ Wh_b,   // [512]
    const float* __restrict__ fc_w,   // [24][512]
    const float* __restrict__ fc_b,   // [24]
    const float* __restrict__ sclq,   // [512] dequant scale (incl. 1/127 h-scale)
    const void*  __restrict__ Wpk8,   // 256 KB packed int8 fragments
    float* __restrict__ out)          // [1024][24]
{
    // int8 h, B-frag layout, double-buffered: hq[buf][kk][lane][16B]
    __shared__ __align__(16) char  hq[2][NKK * 64 * 16];   // 2 x 8 KB
    __shared__ float xs[TSTEPS * BBLK];                     // 16 KB (f32 x)
    __shared__ float tabs[3 * HIDDEN];                      // 6 KB: scale|wxw|bias

    const int tid  = threadIdx.x;
    const int lane = tid & 63;
    const int wave = tid >> 6;       // 0..7, owns tiles 4w..4w+3
    const int bb   = blockIdx.x * BBLK;
    const int arow = lane & 15;      // C/D col = batch row
    const int rowg = lane >> 4;

    // stage x transposed (f32): xs[t*16 + r]
    for (int i = tid; i < BBLK * TSTEPS; i += NTHR) {
        int t = i & 255, r = i >> 8;
        xs[t * 16 + r] = x[(bb + r) * TSTEPS + t];
    }
    // h0 = 0 (both buffers: 16 KB = 1024 vec4)
    {
        i32x4 z = {0, 0, 0, 0};
        i32x4* p = (i32x4*)hq;
        p[tid] = z; p[tid + NTHR] = z;
    }
    // tables
    if (tid < HIDDEN) {
        tabs[tid]              = sclq[tid];
        tabs[HIDDEN + tid]     = Wx_w[tid];
        tabs[2 * HIDDEN + tid] = Wx_b[tid] + Wh_b[tid];
    }

    // SRSRC over the 256 KB packed-weight buffer
    uint4v srsrc;
    {
        unsigned long long b = (unsigned long long)Wpk8;
        srsrc[0] = (unsigned int)b;
        srsrc[1] = (unsigned int)(b >> 32);
        srsrc[2] = 256 * 1024;          // num_records bytes
        srsrc[3] = 0x00020000;
    }
    // stream voffsets: tile (wave*4+s), slice 0: byte = tile*8192 + lane*16
    unsigned int vo0 = ((wave * 4 + 0) * 512 + lane) * 16;
    unsigned int vo1 = ((wave * 4 + 1) * 512 + lane) * 16;
    unsigned int vo2 = ((wave * 4 + 2) * 512 + lane) * 16;
    unsigned int vo3 = ((wave * 4 + 3) * 512 + lane) * 16;

    __syncthreads();   // init visible; compiler VMEM drained

    // persistent prologue: slices 0..3 for all 4 streams (16 loads in flight)
    i32x4 s0[4], s1[4], s2[4], s3[4];
    LOADW4(s0[0], s1[0], s2[0], s3[0], "0x400");
    LOADW4(s0[1], s1[1], s2[1], s3[1], "0x400");
    LOADW4(s0[2], s1[2], s2[2], s3[2], "0x400");
    LOADW4(s0[3], s1[3], s2[3], s3[3], "0x400");   // voff -> slice 4

#pragma clang loop unroll(disable)
    for (int t = 0; t < TSTEPS - 1; ++t) {
        const char* hr = hq[t & 1];
        char*       hw = hq[(t + 1) & 1];

        i32x4 bf[2];
        bf[0] = *(const i32x4*)(hr + 0 * 1024 + lane * 16);
        bf[1] = *(const i32x4*)(hr + 1 * 1024 + lane * 16);
        const float xv = xs[t * 16 + arow];
        i32x4 acc0 = {0,0,0,0}, acc1 = {0,0,0,0}, acc2 = {0,0,0,0}, acc3 = {0,0,0,0};

        // iters 0..3 issue slices 4..7 (this step); iter 3 wraps voff;
        // iters 4..7 issue slices 0..3 (NEXT step) — mature across barrier.
        ITERP(0, "0x400", 1);
        ITERP(1, "0x400", 1);
        ITERP(2, "0x400", 1);
        ITERP(3, "0xffffe400", 1);   // 1024-8192: wrap to slice 0
        ITERP(4, "0x400", 1);
        ITERP(5, "0x400", 1);
        ITERP(6, "0x400", 0);
        ITERP(7, "0x400", 0);        // voff -> slice 4 for next step

        // epilogue: dequant, tanh, re-quantize h to int8, frag-major write.
        // oc = wave*64 + mt*16 + rowg*4 + r  ->  slice=wave, lane'=mt*16+(lane&15),
        // bytes rowg*4..+3.
        {
            i32x4 accs[4] = {acc0, acc1, acc2, acc3};
#pragma unroll
            for (int mt = 0; mt < 4; ++mt) {
                int ocb = wave * 64 + mt * 16 + rowg * 4;
                f32x4 scl = *(const f32x4*)&tabs[ocb];
                f32x4 wx  = *(const f32x4*)&tabs[HIDDEN + ocb];
                f32x4 bs  = *(const f32x4*)&tabs[2 * HIDDEN + ocb];
                unsigned int u = 0;
#pragma unroll
                for (int r = 0; r < 4; ++r) {
                    float z  = xv * wx[r] + scl[r] * (float)accs[mt][r] + bs[r];
                    float e  = __expf(2.0f * z);
                    float th = 1.0f - 2.0f / (e + 1.0f);
                    int q = __float2int_rn(th * 127.0f);
                    u |= (unsigned int)(q & 255) << (8 * r);
                }
                *(unsigned int*)(hw + (wave * 64 + mt * 16 + (lane & 15)) * 16 + rowg * 4) = u;
            }
        }
        lds_barrier();
    }

    // ---- peeled last step: drain to vmcnt 0, write final h as bf16 ----
    {
        const char* hr = hq[(TSTEPS - 1) & 1];
        i32x4 bf[2];
        bf[0] = *(const i32x4*)(hr + 0 * 1024 + lane * 16);
        bf[1] = *(const i32x4*)(hr + 1 * 1024 + lane * 16);
        const float xv = xs[(TSTEPS - 1) * 16 + arow];
        i32x4 acc0 = {0,0,0,0}, acc1 = {0,0,0,0}, acc2 = {0,0,0,0}, acc3 = {0,0,0,0};

        ITERP(0, "0x400", 1);
        ITERP(1, "0x400", 1);
        ITERP(2, "0x400", 1);
        ITERP(3, "0x400", 1);        // no wrap needed; stream ends
        ITERD(4, 12, 1);
        ITERD(5, 8,  1);
        ITERD(6, 4,  0);
        ITERD(7, 0,  0);             // vmcnt == 0: stream fully drained

        lds_barrier();               // all waves' reads done before overwrite

        // final h in bf16, plain [b][k] layout over the hq area (16 KB)
        unsigned short* hout = (unsigned short*)hq;
        i32x4 accs[4] = {acc0, acc1, acc2, acc3};
#pragma unroll
        for (int mt = 0; mt < 4; ++mt) {
            int ocb = wave * 64 + mt * 16 + rowg * 4;
            f32x4 scl = *(const f32x4*)&tabs[ocb];
            f32x4 wx  = *(const f32x4*)&tabs[HIDDEN + ocb];
            f32x4 bs  = *(const f32x4*)&tabs[2 * HIDDEN + ocb];
            us4 pk;
#pragma unroll
            for (int r = 0; r < 4; ++r) {
                float z  = xv * wx[r] + scl[r] * (float)accs[mt][r] + bs[r];
                float e  = __expf(2.0f * z);
                pk[r] = f2bf(1.0f - 2.0f / (e + 1.0f));
            }
            *(us4*)(hout + (lane & 15) * HIDDEN + ocb) = pk;
        }
        lds_barrier();
    }

    // fc head: 16 x 24 outputs from bf16 h
    if (tid < BBLK * HORIZON) {
        int row = tid / HORIZON;
        int ho  = tid - row * HORIZON;
        float acc = fc_b[ho];
        const float* fw = fc_w + ho * HIDDEN;
        const unsigned short* hf = (const unsigned short*)hq;
#pragma unroll 8
        for (int k = 0; k < HIDDEN; k += 8) {
            ushort8 hv = *(const ushort8*)(hf + row * HIDDEN + k);
#pragma unroll
            for (int j = 0; j < 8; ++j)
                acc += bf2f(hv[j]) * fw[k + j];
        }
        out[(bb + row) * HORIZON + ho] = acc;
    }
}

extern "C" void kernel_launch(void* const* d_in, const int* in_sizes, int n_in,
                              void* d_out, int out_size, void* d_ws, size_t ws_size,
                              hipStream_t stream) {
    const float* x    = (const float*)d_in[0];
    const float* Wx_w = (const float*)d_in[1];
    const float* Wx_b = (const float*)d_in[2];
    const float* Wh_w = (const float*)d_in[3];
    const float* Wh_b = (const float*)d_in[4];
    const float* fc_w = (const float*)d_in[5];
    const float* fc_b = (const float*)d_in[6];
    float* out = (float*)d_out;

    // workspace layout: [0,256K) int8 fragments; then invq[512], sclq[512]
    i32x4* Wpk8 = (i32x4*)d_ws;
    float* invq = (float*)((char*)d_ws + 256 * 1024);
    float* sclq = invq + HIDDEN;

    hipLaunchKernelGGL(pack_scales, dim3(HIDDEN), dim3(64), 0, stream, Wh_w, invq, sclq);
    hipLaunchKernelGGL(pack_q, dim3(64), dim3(256), 0, stream, Wh_w, invq, Wpk8);
    hipLaunchKernelGGL(rnn_main, dim3(NWG), dim3(NTHR), 0, stream,
                       x, Wx_w, Wx_b, Wh_b, fc_w, fc_b, sclq,
                       (const void*)Wpk8, out);
}

// Round 10
// 585.959 us; speedup vs baseline: 2.5925x; 1.2307x over previous
//
#include <hip/hip_runtime.h>
#include <hip/hip_bf16.h>

#define HIDDEN   512
#define TSTEPS   256
#define HORIZON  24
#define BTOT     1024
#define BBLK     16
#define NWG      (BTOT / BBLK)      // 64 workgroups
#define NTHR     512                // 8 waves, 4 m-tiles each
#define NKK      8                  // K slices (512 / 64)

typedef __attribute__((ext_vector_type(4))) int            i32x4;
typedef __attribute__((ext_vector_type(4))) float          f32x4;
typedef __attribute__((ext_vector_type(8))) unsigned short ushort8;
typedef __attribute__((ext_vector_type(4))) unsigned short us4;
typedef __attribute__((ext_vector_type(4))) unsigned int   uint4v;

__device__ __forceinline__ unsigned short f2bf(float f) {
    unsigned int u = __float_as_uint(f);
    u += 0x7FFFu + ((u >> 16) & 1u);   // RNE
    return (unsigned short)(u >> 16);
}
__device__ __forceinline__ float bf2f(unsigned short s) {
    return __uint_as_float(((unsigned int)s) << 16);
}

// LDS-ordering-only barrier (no vmcnt drain): weight stream stays in flight.
__device__ __forceinline__ void lds_barrier() {
    asm volatile("s_waitcnt lgkmcnt(0)" ::: "memory");
    __builtin_amdgcn_s_barrier();
    asm volatile("" ::: "memory");
}

// Issue one k-slice for all 4 m-tile streams; self-incrementing voffsets.
#define LOADW4(d0, d1, d2, d3, INCSTR)                               \
    asm volatile("buffer_load_dwordx4 %0, %4, %8, 0 offen\n\t"       \
                 "buffer_load_dwordx4 %1, %5, %8, 0 offen\n\t"       \
                 "buffer_load_dwordx4 %2, %6, %8, 0 offen\n\t"       \
                 "buffer_load_dwordx4 %3, %7, %8, 0 offen\n\t"       \
                 "v_add_u32 %4, " INCSTR ", %4\n\t"                  \
                 "v_add_u32 %5, " INCSTR ", %5\n\t"                  \
                 "v_add_u32 %6, " INCSTR ", %6\n\t"                  \
                 "v_add_u32 %7, " INCSTR ", %7"                      \
                 : "=&v"(d0), "=&v"(d1), "=&v"(d2), "=&v"(d3),       \
                   "+v"(vo0), "+v"(vo1), "+v"(vo2), "+v"(vo3)        \
                 : "s"(srsrc))

#define WAIT4(a, b, c, d, N) \
    asm volatile("s_waitcnt vmcnt(" #N ")" : "+v"(a), "+v"(b), "+v"(c), "+v"(d))

// LDS-resident slice iteration: 4 MFMAs off the 2-deep wv pipe; refill wv two
// slices ahead (PRE only for k=0,1); bf (h) pipe always 2 ahead.
#define ITERL(k, PRE) {                                                         \
    i32x4 bfc = bf[(k) & 1];                                                    \
    acc0 = __builtin_amdgcn_mfma_i32_16x16x64_i8(wv[(k) & 1][0], bfc, acc0, 0, 0, 0); \
    acc1 = __builtin_amdgcn_mfma_i32_16x16x64_i8(wv[(k) & 1][1], bfc, acc1, 0, 0, 0); \
    acc2 = __builtin_amdgcn_mfma_i32_16x16x64_i8(wv[(k) & 1][2], bfc, acc2, 0, 0, 0); \
    acc3 = __builtin_amdgcn_mfma_i32_16x16x64_i8(wv[(k) & 1][3], bfc, acc3, 0, 0, 0); \
    if (PRE) {                                                                  \
        wv[(k) & 1][0] = *(const i32x4*)(wb + 0 * 4096 + ((k) + 2) * 1024);     \
        wv[(k) & 1][1] = *(const i32x4*)(wb + 1 * 4096 + ((k) + 2) * 1024);     \
        wv[(k) & 1][2] = *(const i32x4*)(wb + 2 * 4096 + ((k) + 2) * 1024);     \
        wv[(k) & 1][3] = *(const i32x4*)(wb + 3 * 4096 + ((k) + 2) * 1024);     \
    }                                                                           \
    bf[(k) & 1] = *(const i32x4*)(hr + ((k) + 2) * 1024 + lane * 16); }

// Streamed slice iteration: counted wait (16 in flight, oldest 4 done),
// 4 MFMAs, re-issue the same slice for the NEXT step (full-step lead time).
#define ITERV(k, INCSTR, DOLD) {                                                \
    WAIT4(s0[(k) & 3], s1[(k) & 3], s2[(k) & 3], s3[(k) & 3], 12);              \
    i32x4 bfc = bf[(k) & 1];                                                    \
    acc0 = __builtin_amdgcn_mfma_i32_16x16x64_i8(s0[(k) & 3], bfc, acc0, 0, 0, 0); \
    acc1 = __builtin_amdgcn_mfma_i32_16x16x64_i8(s1[(k) & 3], bfc, acc1, 0, 0, 0); \
    acc2 = __builtin_amdgcn_mfma_i32_16x16x64_i8(s2[(k) & 3], bfc, acc2, 0, 0, 0); \
    acc3 = __builtin_amdgcn_mfma_i32_16x16x64_i8(s3[(k) & 3], bfc, acc3, 0, 0, 0); \
    if (DOLD) bf[(k) & 1] = *(const i32x4*)(hr + ((k) + 2) * 1024 + lane * 16); \
    LOADW4(s0[(k) & 3], s1[(k) & 3], s2[(k) & 3], s3[(k) & 3], INCSTR); }

// Drain iteration (last step): counted wait, no re-issue.
#define ITERD(k, N, DOLD) {                                                     \
    WAIT4(s0[(k) & 3], s1[(k) & 3], s2[(k) & 3], s3[(k) & 3], N);               \
    i32x4 bfc = bf[(k) & 1];                                                    \
    acc0 = __builtin_amdgcn_mfma_i32_16x16x64_i8(s0[(k) & 3], bfc, acc0, 0, 0, 0); \
    acc1 = __builtin_amdgcn_mfma_i32_16x16x64_i8(s1[(k) & 3], bfc, acc1, 0, 0, 0); \
    acc2 = __builtin_amdgcn_mfma_i32_16x16x64_i8(s2[(k) & 3], bfc, acc2, 0, 0, 0); \
    acc3 = __builtin_amdgcn_mfma_i32_16x16x64_i8(s3[(k) & 3], bfc, acc3, 0, 0, 0); \
    if (DOLD) bf[(k) & 1] = *(const i32x4*)(hr + ((k) + 2) * 1024 + lane * 16); }

// ---- prep 1: per-out-col scales ----
__global__ void pack_scales(const float* __restrict__ Wh,
                            float* __restrict__ invq,    // 127/max
                            float* __restrict__ sclq) {  // max/(127*127)
    int oc   = blockIdx.x;
    int lane = threadIdx.x;
    float m = 0.f;
#pragma unroll
    for (int j = 0; j < 8; ++j) m = fmaxf(m, fabsf(Wh[oc * HIDDEN + lane * 8 + j]));
    for (int d = 1; d < 64; d <<= 1) m = fmaxf(m, __shfl_xor(m, d));
    if (lane == 0) {
        float inv = (m > 0.f) ? 127.0f / m : 0.f;
        invq[oc] = inv;
        sclq[oc] = m / (127.0f * 127.0f);
    }
}

// ---- prep 2: quantize + pack into i8 A-fragment order.
// Frag (tile, kk, lane): 16 int8 of A[oc=tile*16+(lane&15)][k=kk*64+(lane>>4)*16+j]
__global__ void pack_q(const float* __restrict__ Wh,
                       const float* __restrict__ invq,
                       i32x4* __restrict__ Wpk8) {
    int tid  = blockIdx.x * blockDim.x + threadIdx.x;   // 0..16383
    int lane = tid & 63;
    int kk   = (tid >> 6) & 7;
    int mt   = tid >> 9;                                 // global tile 0..31
    int oc   = mt * 16 + (lane & 15);
    int k0   = kk * 64 + (lane >> 4) * 16;
    float inv = invq[oc];
    const float* src = Wh + oc * HIDDEN + k0;
    int w[4];
#pragma unroll
    for (int d = 0; d < 4; ++d) {
        int b0 = __float2int_rn(src[d * 4 + 0] * inv) & 255;
        int b1 = __float2int_rn(src[d * 4 + 1] * inv) & 255;
        int b2 = __float2int_rn(src[d * 4 + 2] * inv) & 255;
        int b3 = __float2int_rn(src[d * 4 + 3] * inv) & 255;
        w[d] = b0 | (b1 << 8) | (b2 << 16) | (b3 << 24);
    }
    i32x4 v = {w[0], w[1], w[2], w[3]};
    Wpk8[(mt * 8 + kk) * 64 + lane] = v;
}

__global__ __launch_bounds__(NTHR) void rnn_main(
    const float* __restrict__ x,      // [1024][256]
    const float* __restrict__ Wx_w,   // [512]
    const float* __restrict__ Wx_b,   // [512]
    const float* __restrict__ Wh_b,   // [512]
    const float* __restrict__ fc_w,   // [24][512]
    const float* __restrict__ fc_b,   // [24]
    const float* __restrict__ sclq,   // [512] dequant scale
    const void*  __restrict__ Wpk8,   // 256 KB packed int8 fragments
    float* __restrict__ out)          // [1024][24]
{
    // LDS: W slices 0..3 resident (128 KB) + int8 h dbuf + bf16 x + tables
    __shared__ __align__(16) char  wlds[4 * 32 * 64 * 16];      // 128 KB
    __shared__ __align__(16) char  hq[2][NKK * 64 * 16];        // 16 KB
    __shared__ __align__(16) unsigned short xsb[TSTEPS * BBLK]; // 8 KB
    __shared__ __align__(16) float tabs[3 * HIDDEN];            // 6 KB

    const int tid  = threadIdx.x;
    const int lane = tid & 63;
    const int wave = tid >> 6;       // 0..7, owns tiles 4w..4w+3
    const int bb   = blockIdx.x * BBLK;
    const int arow = lane & 15;      // C/D col = batch row
    const int rowg = lane >> 4;

    // stage x transposed as bf16: xsb[t*16 + r]
    for (int i = tid; i < BBLK * TSTEPS; i += NTHR) {
        int t = i & 255, r = i >> 8;
        xsb[t * 16 + r] = f2bf(x[(bb + r) * TSTEPS + t]);
    }
    // stage W slices 0..3 into LDS: wlds[(mt*4+kk)*64+lane] = Wpk8[(mt*8+kk)*64+lane]
    {
        const i32x4* Wg = (const i32x4*)Wpk8;
        i32x4* WL = (i32x4*)wlds;
        for (int i = tid; i < 8192; i += NTHR) {
            int mt = i >> 8;
            WL[i] = Wg[i + mt * 256];
        }
    }
    // h0 = 0 (both buffers: 16 KB = 1024 vec4)
    {
        i32x4 z = {0, 0, 0, 0};
        i32x4* p = (i32x4*)hq;
        p[tid] = z; p[tid + NTHR] = z;
    }
    // tables
    if (tid < HIDDEN) {
        tabs[tid]              = sclq[tid];
        tabs[HIDDEN + tid]     = Wx_w[tid];
        tabs[2 * HIDDEN + tid] = Wx_b[tid] + Wh_b[tid];
    }

    // SRSRC over the 256 KB packed-weight buffer
    uint4v srsrc;
    {
        unsigned long long b = (unsigned long long)Wpk8;
        srsrc[0] = (unsigned int)b;
        srsrc[1] = (unsigned int)(b >> 32);
        srsrc[2] = 256 * 1024;          // num_records bytes
        srsrc[3] = 0x00020000;
    }
    // stream voffsets start at slice 4: byte = tile*8192 + 4*64*16 + lane*16
    unsigned int vo0 = ((wave * 4 + 0) * 512 + 256 + lane) * 16;
    unsigned int vo1 = ((wave * 4 + 1) * 512 + 256 + lane) * 16;
    unsigned int vo2 = ((wave * 4 + 2) * 512 + 256 + lane) * 16;
    unsigned int vo3 = ((wave * 4 + 3) * 512 + 256 + lane) * 16;

    __syncthreads();   // staging visible; compiler VMEM drained

    // persistent prologue: slices 4..7 for all 4 tile-streams (16 in flight)
    i32x4 s0[4], s1[4], s2[4], s3[4];
    LOADW4(s0[0], s1[0], s2[0], s3[0], "0x400");       // slice 4
    LOADW4(s0[1], s1[1], s2[1], s3[1], "0x400");       // slice 5
    LOADW4(s0[2], s1[2], s2[2], s3[2], "0x400");       // slice 6
    LOADW4(s0[3], s1[3], s2[3], s3[3], "0xfffff400");  // slice 7, wrap vo->slice 4

    const char* wb = wlds + wave * 16384 + lane * 16;

#pragma clang loop unroll(disable)
    for (int t = 0; t < TSTEPS - 1; ++t) {
        const char* hr = hq[t & 1];
        char*       hw = hq[(t + 1) & 1];

        // 2-deep pipes: W-LDS (slices 0,1) and h (slices 0,1)
        i32x4 wv[2][4];
#pragma unroll
        for (int s = 0; s < 4; ++s) {
            wv[0][s] = *(const i32x4*)(wb + s * 4096 + 0 * 1024);
            wv[1][s] = *(const i32x4*)(wb + s * 4096 + 1 * 1024);
        }
        i32x4 bf[2];
        bf[0] = *(const i32x4*)(hr + 0 * 1024 + lane * 16);
        bf[1] = *(const i32x4*)(hr + 1 * 1024 + lane * 16);
        const float xv = bf2f(xsb[t * 16 + arow]);
        i32x4 acc0 = {0,0,0,0}, acc1 = {0,0,0,0}, acc2 = {0,0,0,0}, acc3 = {0,0,0,0};

        ITERL(0, 1);
        ITERL(1, 1);
        ITERL(2, 0);
        ITERL(3, 0);
        ITERV(4, "0x400", 1);
        ITERV(5, "0x400", 1);
        ITERV(6, "0x400", 0);
        ITERV(7, "0xfffff400", 0);   // wrap vo back to slice 4 for next step

        // epilogue: dequant, tanh, re-quantize h, frag-major write
        {
            i32x4 accs[4] = {acc0, acc1, acc2, acc3};
#pragma unroll
            for (int mt = 0; mt < 4; ++mt) {
                int ocb = wave * 64 + mt * 16 + rowg * 4;
                f32x4 scl = *(const f32x4*)&tabs[ocb];
                f32x4 wx  = *(const f32x4*)&tabs[HIDDEN + ocb];
                f32x4 bs  = *(const f32x4*)&tabs[2 * HIDDEN + ocb];
                unsigned int u = 0;
#pragma unroll
                for (int r = 0; r < 4; ++r) {
                    float z  = xv * wx[r] + scl[r] * (float)accs[mt][r] + bs[r];
                    float e  = __expf(2.0f * z);
                    float th = 1.0f - 2.0f / (e + 1.0f);
                    int q = __float2int_rn(th * 127.0f);
                    u |= (unsigned int)(q & 255) << (8 * r);
                }
                *(unsigned int*)(hw + (wave * 64 + mt * 16 + (lane & 15)) * 16 + rowg * 4) = u;
            }
        }
        lds_barrier();
    }

    // ---- peeled last step: drain to vmcnt 0, write final h as bf16 ----
    {
        const char* hr = hq[(TSTEPS - 1) & 1];
        i32x4 wv[2][4];
#pragma unroll
        for (int s = 0; s < 4; ++s) {
            wv[0][s] = *(const i32x4*)(wb + s * 4096 + 0 * 1024);
            wv[1][s] = *(const i32x4*)(wb + s * 4096 + 1 * 1024);
        }
        i32x4 bf[2];
        bf[0] = *(const i32x4*)(hr + 0 * 1024 + lane * 16);
        bf[1] = *(const i32x4*)(hr + 1 * 1024 + lane * 16);
        const float xv = bf2f(xsb[(TSTEPS - 1) * 16 + arow]);
        i32x4 acc0 = {0,0,0,0}, acc1 = {0,0,0,0}, acc2 = {0,0,0,0}, acc3 = {0,0,0,0};

        ITERL(0, 1);
        ITERL(1, 1);
        ITERL(2, 0);
        ITERL(3, 0);
        ITERD(4, 12, 1);
        ITERD(5, 8,  1);
        ITERD(6, 4,  0);
        ITERD(7, 0,  0);             // vmcnt == 0: stream fully drained

        lds_barrier();               // all reads done before overwrite

        // final h in bf16, plain [b][k] layout over the hq area (16 KB)
        unsigned short* hout = (unsigned short*)hq;
        i32x4 accs[4] = {acc0, acc1, acc2, acc3};
#pragma unroll
        for (int mt = 0; mt < 4; ++mt) {
            int ocb = wave * 64 + mt * 16 + rowg * 4;
            f32x4 scl = *(const f32x4*)&tabs[ocb];
            f32x4 wx  = *(const f32x4*)&tabs[HIDDEN + ocb];
            f32x4 bs  = *(const f32x4*)&tabs[2 * HIDDEN + ocb];
            us4 pk;
#pragma unroll
            for (int r = 0; r < 4; ++r) {
                float z  = xv * wx[r] + scl[r] * (float)accs[mt][r] + bs[r];
                float e  = __expf(2.0f * z);
                pk[r] = f2bf(1.0f - 2.0f / (e + 1.0f));
            }
            *(us4*)(hout + (lane & 15) * HIDDEN + ocb) = pk;
        }
        lds_barrier();
    }

    // fc head: 16 x 24 outputs from bf16 h
    if (tid < BBLK * HORIZON) {
        int row = tid / HORIZON;
        int ho  = tid - row * HORIZON;
        float acc = fc_b[ho];
        const float* fw = fc_w + ho * HIDDEN;
        const unsigned short* hf = (const unsigned short*)hq;
#pragma unroll 8
        for (int k = 0; k < HIDDEN; k += 8) {
            ushort8 hv = *(const ushort8*)(hf + row * HIDDEN + k);
#pragma unroll
            for (int j = 0; j < 8; ++j)
                acc += bf2f(hv[j]) * fw[k + j];
        }
        out[(bb + row) * HORIZON + ho] = acc;
    }
}

extern "C" void kernel_launch(void* const* d_in, const int* in_sizes, int n_in,
                              void* d_out, int out_size, void* d_ws, size_t ws_size,
                              hipStream_t stream) {
    const float* x    = (const float*)d_in[0];
    const float* Wx_w = (const float*)d_in[1];
    const float* Wx_b = (const float*)d_in[2];
    const float* Wh_w = (const float*)d_in[3];
    const float* Wh_b = (const float*)d_in[4];
    const float* fc_w = (const float*)d_in[5];
    const float* fc_b = (const float*)d_in[6];
    float* out = (float*)d_out;

    // workspace: [0,256K) int8 fragments; then invq[512], sclq[512]
    i32x4* Wpk8 = (i32x4*)d_ws;
    float* invq = (float*)((char*)d_ws + 256 * 1024);
    float* sclq = invq + HIDDEN;

    hipLaunchKernelGGL(pack_scales, dim3(HIDDEN), dim3(64), 0, stream, Wh_w, invq, sclq);
    hipLaunchKernelGGL(pack_q, dim3(64), dim3(256), 0, stream, Wh_w, invq, Wpk8);
    hipLaunchKernelGGL(rnn_main, dim3(NWG), dim3(NTHR), 0, stream,
                       x, Wx_w, Wx_b, Wh_b, fc_w, fc_b, sclq,
                       (const void*)Wpk8, out);
}

// Round 11
// 424.939 us; speedup vs baseline: 3.5748x; 1.3789x over previous
//
#include <hip/hip_runtime.h>
#include <hip/hip_bf16.h>

#define HIDDEN   512
#define TSTEPS   256
#define HORIZON  24
#define BTOT     1024
#define BBLK     16
#define NWG      (BTOT / BBLK)      // 64 workgroups
#define NTHR     512                // 8 waves, 4 m-tiles each
#define NKK      8                  // K slices (512 / 64)

typedef __attribute__((ext_vector_type(4))) int            i32x4;
typedef __attribute__((ext_vector_type(4))) float          f32x4;
typedef __attribute__((ext_vector_type(8))) unsigned short ushort8;
typedef __attribute__((ext_vector_type(4))) unsigned short us4;
typedef __attribute__((ext_vector_type(4))) unsigned int   uint4v;

#define LOG2E2 2.8853900817779268f   // 2*log2(e): exp(2z) = exp2(z*LOG2E2)

__device__ __forceinline__ unsigned short f2bf(float f) {
    unsigned int u = __float_as_uint(f);
    u += 0x7FFFu + ((u >> 16) & 1u);   // RNE
    return (unsigned short)(u >> 16);
}
__device__ __forceinline__ float bf2f(unsigned short s) {
    return __uint_as_float(((unsigned int)s) << 16);
}

// LDS-ordering-only barrier (no vmcnt drain): weight stream stays in flight.
__device__ __forceinline__ void lds_barrier() {
    asm volatile("s_waitcnt lgkmcnt(0)" ::: "memory");
    __builtin_amdgcn_s_barrier();
    asm volatile("" ::: "memory");
}

// Issue one k-slice for all 4 m-tile streams; self-incrementing voffsets.
#define LOADW4(d0, d1, d2, d3, INCSTR)                               \
    asm volatile("buffer_load_dwordx4 %0, %4, %8, 0 offen\n\t"       \
                 "buffer_load_dwordx4 %1, %5, %8, 0 offen\n\t"       \
                 "buffer_load_dwordx4 %2, %6, %8, 0 offen\n\t"       \
                 "buffer_load_dwordx4 %3, %7, %8, 0 offen\n\t"       \
                 "v_add_u32 %4, " INCSTR ", %4\n\t"                  \
                 "v_add_u32 %5, " INCSTR ", %5\n\t"                  \
                 "v_add_u32 %6, " INCSTR ", %6\n\t"                  \
                 "v_add_u32 %7, " INCSTR ", %7"                      \
                 : "=&v"(d0), "=&v"(d1), "=&v"(d2), "=&v"(d3),       \
                   "+v"(vo0), "+v"(vo1), "+v"(vo2), "+v"(vo3)        \
                 : "s"(srsrc))

#define WAIT4(a, b, c, d, N) \
    asm volatile("s_waitcnt vmcnt(" #N ")" : "+v"(a), "+v"(b), "+v"(c), "+v"(d))

// LDS-resident slice iteration: 4 MFMAs off the 2-deep wv pipe; refill wv two
// slices ahead (PRE only for k=0,1); bf (h) pipe always 2 ahead.
#define ITERL(k, PRE) {                                                         \
    i32x4 bfc = bf[(k) & 1];                                                    \
    acc0 = __builtin_amdgcn_mfma_i32_16x16x64_i8(wv[(k) & 1][0], bfc, acc0, 0, 0, 0); \
    acc1 = __builtin_amdgcn_mfma_i32_16x16x64_i8(wv[(k) & 1][1], bfc, acc1, 0, 0, 0); \
    acc2 = __builtin_amdgcn_mfma_i32_16x16x64_i8(wv[(k) & 1][2], bfc, acc2, 0, 0, 0); \
    acc3 = __builtin_amdgcn_mfma_i32_16x16x64_i8(wv[(k) & 1][3], bfc, acc3, 0, 0, 0); \
    if (PRE) {                                                                  \
        wv[(k) & 1][0] = *(const i32x4*)(wb + 0 * 4096 + ((k) + 2) * 1024);     \
        wv[(k) & 1][1] = *(const i32x4*)(wb + 1 * 4096 + ((k) + 2) * 1024);     \
        wv[(k) & 1][2] = *(const i32x4*)(wb + 2 * 4096 + ((k) + 2) * 1024);     \
        wv[(k) & 1][3] = *(const i32x4*)(wb + 3 * 4096 + ((k) + 2) * 1024);     \
    }                                                                           \
    bf[(k) & 1] = *(const i32x4*)(hr + ((k) + 2) * 1024 + lane * 16); }

// Streamed slice iteration: counted wait (16 in flight, oldest 4 done),
// 4 MFMAs, re-issue the same slice for the NEXT step (full-step lead time).
#define ITERV(k, INCSTR, DOLD) {                                                \
    WAIT4(s0[(k) & 3], s1[(k) & 3], s2[(k) & 3], s3[(k) & 3], 12);              \
    i32x4 bfc = bf[(k) & 1];                                                    \
    acc0 = __builtin_amdgcn_mfma_i32_16x16x64_i8(s0[(k) & 3], bfc, acc0, 0, 0, 0); \
    acc1 = __builtin_amdgcn_mfma_i32_16x16x64_i8(s1[(k) & 3], bfc, acc1, 0, 0, 0); \
    acc2 = __builtin_amdgcn_mfma_i32_16x16x64_i8(s2[(k) & 3], bfc, acc2, 0, 0, 0); \
    acc3 = __builtin_amdgcn_mfma_i32_16x16x64_i8(s3[(k) & 3], bfc, acc3, 0, 0, 0); \
    if (DOLD) bf[(k) & 1] = *(const i32x4*)(hr + ((k) + 2) * 1024 + lane * 16); \
    LOADW4(s0[(k) & 3], s1[(k) & 3], s2[(k) & 3], s3[(k) & 3], INCSTR); }

// Drain iteration (last step): counted wait, no re-issue.
#define ITERD(k, N, DOLD) {                                                     \
    WAIT4(s0[(k) & 3], s1[(k) & 3], s2[(k) & 3], s3[(k) & 3], N);               \
    i32x4 bfc = bf[(k) & 1];                                                    \
    acc0 = __builtin_amdgcn_mfma_i32_16x16x64_i8(s0[(k) & 3], bfc, acc0, 0, 0, 0); \
    acc1 = __builtin_amdgcn_mfma_i32_16x16x64_i8(s1[(k) & 3], bfc, acc1, 0, 0, 0); \
    acc2 = __builtin_amdgcn_mfma_i32_16x16x64_i8(s2[(k) & 3], bfc, acc2, 0, 0, 0); \
    acc3 = __builtin_amdgcn_mfma_i32_16x16x64_i8(s3[(k) & 3], bfc, acc3, 0, 0, 0); \
    if (DOLD) bf[(k) & 1] = *(const i32x4*)(hr + ((k) + 2) * 1024 + lane * 16); }

// ---- prep 1: per-out-col scales ----
__global__ void pack_scales(const float* __restrict__ Wh,
                            float* __restrict__ invq,    // 127/max
                            float* __restrict__ sclq) {  // max/(127*127)
    int oc   = blockIdx.x;
    int lane = threadIdx.x;
    float m = 0.f;
#pragma unroll
    for (int j = 0; j < 8; ++j) m = fmaxf(m, fabsf(Wh[oc * HIDDEN + lane * 8 + j]));
    for (int d = 1; d < 64; d <<= 1) m = fmaxf(m, __shfl_xor(m, d));
    if (lane == 0) {
        float inv = (m > 0.f) ? 127.0f / m : 0.f;
        invq[oc] = inv;
        sclq[oc] = m / (127.0f * 127.0f);
    }
}

// ---- prep 2: quantize + pack into i8 A-fragment order.
// Frag (tile, kk, lane): 16 int8 of A[oc=tile*16+(lane&15)][k=kk*64+(lane>>4)*16+j]
__global__ void pack_q(const float* __restrict__ Wh,
                       const float* __restrict__ invq,
                       i32x4* __restrict__ Wpk8) {
    int tid  = blockIdx.x * blockDim.x + threadIdx.x;   // 0..16383
    int lane = tid & 63;
    int kk   = (tid >> 6) & 7;
    int mt   = tid >> 9;                                 // global tile 0..31
    int oc   = mt * 16 + (lane & 15);
    int k0   = kk * 64 + (lane >> 4) * 16;
    float inv = invq[oc];
    const float* src = Wh + oc * HIDDEN + k0;
    int w[4];
#pragma unroll
    for (int d = 0; d < 4; ++d) {
        int b0 = __float2int_rn(src[d * 4 + 0] * inv) & 255;
        int b1 = __float2int_rn(src[d * 4 + 1] * inv) & 255;
        int b2 = __float2int_rn(src[d * 4 + 2] * inv) & 255;
        int b3 = __float2int_rn(src[d * 4 + 3] * inv) & 255;
        w[d] = b0 | (b1 << 8) | (b2 << 16) | (b3 << 24);
    }
    i32x4 v = {w[0], w[1], w[2], w[3]};
    Wpk8[(mt * 8 + kk) * 64 + lane] = v;
}

__global__ __launch_bounds__(NTHR)
__attribute__((amdgpu_waves_per_eu(2, 2)))
void rnn_main(
    const float* __restrict__ x,      // [1024][256]
    const float* __restrict__ Wx_w,   // [512]
    const float* __restrict__ Wx_b,   // [512]
    const float* __restrict__ Wh_b,   // [512]
    const float* __restrict__ fc_w,   // [24][512]
    const float* __restrict__ fc_b,   // [24]
    const float* __restrict__ sclq,   // [512] dequant scale
    const void*  __restrict__ Wpk8,   // 256 KB packed int8 fragments
    float* __restrict__ out)          // [1024][24]
{
    // LDS: W slices 0..3 resident (128 KB) + int8 h dbuf + bf16 x
    __shared__ __align__(16) char  wlds[4 * 32 * 64 * 16];      // 128 KB
    __shared__ __align__(16) char  hq[2][NKK * 64 * 16];        // 16 KB
    __shared__ __align__(16) unsigned short xsb[TSTEPS * BBLK]; // 8 KB

    const int tid  = threadIdx.x;
    const int lane = tid & 63;
    const int wave = tid >> 6;       // 0..7, owns tiles 4w..4w+3
    const int bb   = blockIdx.x * BBLK;
    const int arow = lane & 15;      // C/D col = batch row
    const int rowg = lane >> 4;

    // stage x transposed as bf16: xsb[t*16 + r]
    for (int i = tid; i < BBLK * TSTEPS; i += NTHR) {
        int t = i & 255, r = i >> 8;
        xsb[t * 16 + r] = f2bf(x[(bb + r) * TSTEPS + t]);
    }
    // stage W slices 0..3 into LDS: wlds[(mt*4+kk)*64+lane] = Wpk8[(mt*8+kk)*64+lane]
    {
        const i32x4* Wg = (const i32x4*)Wpk8;
        i32x4* WL = (i32x4*)wlds;
        for (int i = tid; i < 8192; i += NTHR) {
            int mt = i >> 8;
            WL[i] = Wg[i + mt * 256];
        }
    }
    // h0 = 0 (both buffers: 16 KB = 1024 vec4)
    {
        i32x4 z = {0, 0, 0, 0};
        i32x4* p = (i32x4*)hq;
        p[tid] = z; p[tid + NTHR] = z;
    }

    // per-thread scale/bias tables in REGISTERS (48 VGPR), loaded once.
    f32x4 scl_r[4], wx_r[4], bs_r[4];
#pragma unroll
    for (int mt = 0; mt < 4; ++mt) {
        int ocb = wave * 64 + mt * 16 + rowg * 4;
        scl_r[mt] = *(const f32x4*)&sclq[ocb];
        wx_r[mt]  = *(const f32x4*)&Wx_w[ocb];
        f32x4 b1  = *(const f32x4*)&Wx_b[ocb];
        f32x4 b2  = *(const f32x4*)&Wh_b[ocb];
        bs_r[mt]  = b1 + b2;
    }

    // SRSRC over the 256 KB packed-weight buffer
    uint4v srsrc;
    {
        unsigned long long b = (unsigned long long)Wpk8;
        srsrc[0] = (unsigned int)b;
        srsrc[1] = (unsigned int)(b >> 32);
        srsrc[2] = 256 * 1024;          // num_records bytes
        srsrc[3] = 0x00020000;
    }
    // stream voffsets start at slice 4: byte = tile*8192 + 4*64*16 + lane*16
    unsigned int vo0 = ((wave * 4 + 0) * 512 + 256 + lane) * 16;
    unsigned int vo1 = ((wave * 4 + 1) * 512 + 256 + lane) * 16;
    unsigned int vo2 = ((wave * 4 + 2) * 512 + 256 + lane) * 16;
    unsigned int vo3 = ((wave * 4 + 3) * 512 + 256 + lane) * 16;

    __syncthreads();   // staging visible; compiler VMEM drained

    // persistent prologue: slices 4..7 for all 4 tile-streams (16 in flight)
    i32x4 s0[4], s1[4], s2[4], s3[4];
    LOADW4(s0[0], s1[0], s2[0], s3[0], "0x400");       // slice 4
    LOADW4(s0[1], s1[1], s2[1], s3[1], "0x400");       // slice 5
    LOADW4(s0[2], s1[2], s2[2], s3[2], "0x400");       // slice 6
    LOADW4(s0[3], s1[3], s2[3], s3[3], "0xfffff400");  // slice 7, wrap vo->slice 4

    const char* wb = wlds + wave * 16384 + lane * 16;

#pragma clang loop unroll(disable)
    for (int t = 0; t < TSTEPS - 1; ++t) {
        const char* hr = hq[t & 1];
        char*       hw = hq[(t + 1) & 1];

        // 2-deep pipes: W-LDS (slices 0,1) and h (slices 0,1)
        i32x4 wv[2][4];
#pragma unroll
        for (int s = 0; s < 4; ++s) {
            wv[0][s] = *(const i32x4*)(wb + s * 4096 + 0 * 1024);
            wv[1][s] = *(const i32x4*)(wb + s * 4096 + 1 * 1024);
        }
        i32x4 bf[2];
        bf[0] = *(const i32x4*)(hr + 0 * 1024 + lane * 16);
        bf[1] = *(const i32x4*)(hr + 1 * 1024 + lane * 16);
        const float xv = bf2f(xsb[t * 16 + arow]);
        i32x4 acc0 = {0,0,0,0}, acc1 = {0,0,0,0}, acc2 = {0,0,0,0}, acc3 = {0,0,0,0};

        ITERL(0, 1);
        ITERL(1, 1);
        ITERL(2, 0);
        ITERL(3, 0);
        ITERV(4, "0x400", 1);
        ITERV(5, "0x400", 1);
        ITERV(6, "0x400", 0);
        ITERV(7, "0xfffff400", 0);   // wrap vo back to slice 4 for next step

        // epilogue: dequant, tanh (rcp, x127 folded), v_perm byte pack, write
        {
            i32x4 accs[4] = {acc0, acc1, acc2, acc3};
#pragma unroll
            for (int mt = 0; mt < 4; ++mt) {
                int q[4];
#pragma unroll
                for (int r = 0; r < 4; ++r) {
                    float z  = fmaf(xv, wx_r[mt][r],
                               fmaf((float)accs[mt][r], scl_r[mt][r], bs_r[mt][r]));
                    float e  = __builtin_amdgcn_exp2f(z * LOG2E2);
                    float rc = __builtin_amdgcn_rcpf(e + 1.0f);
                    q[r] = __float2int_rn(fmaf(-254.0f, rc, 127.0f));  // 127*tanh
                }
                unsigned int u =
                    __builtin_amdgcn_perm((unsigned)q[1], (unsigned)q[0], 0x0C0C0400u) |
                    __builtin_amdgcn_perm((unsigned)q[3], (unsigned)q[2], 0x04000C0Cu);
                *(unsigned int*)(hw + (wave * 64 + mt * 16 + (lane & 15)) * 16 + rowg * 4) = u;
            }
        }
        lds_barrier();
    }

    // ---- peeled last step: drain to vmcnt 0, write final h as bf16 ----
    {
        const char* hr = hq[(TSTEPS - 1) & 1];
        i32x4 wv[2][4];
#pragma unroll
        for (int s = 0; s < 4; ++s) {
            wv[0][s] = *(const i32x4*)(wb + s * 4096 + 0 * 1024);
            wv[1][s] = *(const i32x4*)(wb + s * 4096 + 1 * 1024);
        }
        i32x4 bf[2];
        bf[0] = *(const i32x4*)(hr + 0 * 1024 + lane * 16);
        bf[1] = *(const i32x4*)(hr + 1 * 1024 + lane * 16);
        const float xv = bf2f(xsb[(TSTEPS - 1) * 16 + arow]);
        i32x4 acc0 = {0,0,0,0}, acc1 = {0,0,0,0}, acc2 = {0,0,0,0}, acc3 = {0,0,0,0};

        ITERL(0, 1);
        ITERL(1, 1);
        ITERL(2, 0);
        ITERL(3, 0);
        ITERD(4, 12, 1);
        ITERD(5, 8,  1);
        ITERD(6, 4,  0);
        ITERD(7, 0,  0);             // vmcnt == 0: stream fully drained

        lds_barrier();               // all reads done before overwrite

        // final h in bf16, plain [b][k] layout over the hq area (16 KB)
        unsigned short* hout = (unsigned short*)hq;
        i32x4 accs[4] = {acc0, acc1, acc2, acc3};
#pragma unroll
        for (int mt = 0; mt < 4; ++mt) {
            int ocb = wave * 64 + mt * 16 + rowg * 4;
            us4 pk;
#pragma unroll
            for (int r = 0; r < 4; ++r) {
                float z  = fmaf(xv, wx_r[mt][r],
                           fmaf((float)accs[mt][r], scl_r[mt][r], bs_r[mt][r]));
                float e  = __builtin_amdgcn_exp2f(z * LOG2E2);
                float rc = __builtin_amdgcn_rcpf(e + 1.0f);
                pk[r] = f2bf(fmaf(-2.0f, rc, 1.0f));
            }
            *(us4*)(hout + (lane & 15) * HIDDEN + ocb) = pk;
        }
        lds_barrier();
    }

    // fc head: 16 x 24 outputs from bf16 h
    if (tid < BBLK * HORIZON) {
        int row = tid / HORIZON;
        int ho  = tid - row * HORIZON;
        float acc = fc_b[ho];
        const float* fw = fc_w + ho * HIDDEN;
        const unsigned short* hf = (const unsigned short*)hq;
#pragma unroll 8
        for (int k = 0; k < HIDDEN; k += 8) {
            ushort8 hv = *(const ushort8*)(hf + row * HIDDEN + k);
#pragma unroll
            for (int j = 0; j < 8; ++j)
                acc += bf2f(hv[j]) * fw[k + j];
        }
        out[(bb + row) * HORIZON + ho] = acc;
    }
}

extern "C" void kernel_launch(void* const* d_in, const int* in_sizes, int n_in,
                              void* d_out, int out_size, void* d_ws, size_t ws_size,
                              hipStream_t stream) {
    const float* x    = (const float*)d_in[0];
    const float* Wx_w = (const float*)d_in[1];
    const float* Wx_b = (const float*)d_in[2];
    const float* Wh_w = (const float*)d_in[3];
    const float* Wh_b = (const float*)d_in[4];
    const float* fc_w = (const float*)d_in[5];
    const float* fc_b = (const float*)d_in[6];
    float* out = (float*)d_out;

    // workspace: [0,256K) int8 fragments; then invq[512], sclq[512]
    i32x4* Wpk8 = (i32x4*)d_ws;
    float* invq = (float*)((char*)d_ws + 256 * 1024);
    float* sclq = invq + HIDDEN;

    hipLaunchKernelGGL(pack_scales, dim3(HIDDEN), dim3(64), 0, stream, Wh_w, invq, sclq);
    hipLaunchKernelGGL(pack_q, dim3(64), dim3(256), 0, stream, Wh_w, invq, Wpk8);
    hipLaunchKernelGGL(rnn_main, dim3(NWG), dim3(NTHR), 0, stream,
                       x, Wx_w, Wx_b, Wh_b, fc_w, fc_b, sclq,
                       (const void*)Wpk8, out);
}

// Round 12
// 379.688 us; speedup vs baseline: 4.0009x; 1.1192x over previous
//
#include <hip/hip_runtime.h>
#include <hip/hip_bf16.h>

#define HIDDEN   512
#define TSTEPS   256
#define HORIZON  24
#define BTOT     1024
#define BBLK     16
#define NWG      (BTOT / BBLK)      // 64 workgroups
#define NTHR     1024               // 16 waves, 2 m-tiles each
#define NKK      8                  // K slices (512 / 64)

typedef __attribute__((ext_vector_type(4))) int            i32x4;
typedef __attribute__((ext_vector_type(4))) float          f32x4;
typedef __attribute__((ext_vector_type(8))) unsigned short ushort8;
typedef __attribute__((ext_vector_type(4))) unsigned short us4;
typedef __attribute__((ext_vector_type(4))) unsigned int   uint4v;

#define LOG2E2 2.8853900817779268f   // 2*log2(e): exp(2z) = exp2(z*LOG2E2)

__device__ __forceinline__ unsigned short f2bf(float f) {
    unsigned int u = __float_as_uint(f);
    u += 0x7FFFu + ((u >> 16) & 1u);   // RNE
    return (unsigned short)(u >> 16);
}
__device__ __forceinline__ float bf2f(unsigned short s) {
    return __uint_as_float(((unsigned int)s) << 16);
}

// LDS-ordering-only barrier (no vmcnt drain): weight stream stays in flight.
__device__ __forceinline__ void lds_barrier() {
    asm volatile("s_waitcnt lgkmcnt(0)" ::: "memory");
    __builtin_amdgcn_s_barrier();
    asm volatile("" ::: "memory");
}

// Issue one k-slice for the wave's 2 tile-streams; self-incrementing voffsets.
#define LOADW2(d0, d1, INCSTR)                                       \
    asm volatile("buffer_load_dwordx4 %0, %2, %4, 0 offen\n\t"       \
                 "buffer_load_dwordx4 %1, %3, %4, 0 offen\n\t"       \
                 "v_add_u32 %2, " INCSTR ", %2\n\t"                  \
                 "v_add_u32 %3, " INCSTR ", %3"                      \
                 : "=&v"(d0), "=&v"(d1), "+v"(vo0), "+v"(vo1)        \
                 : "s"(srsrc))

#define WAIT2(a, b, N) \
    asm volatile("s_waitcnt vmcnt(" #N ")" : "+v"(a), "+v"(b))

// LDS-resident slice iteration: 2 MFMAs; refill wv 2 slices ahead (PRE only
// for k=0,1); bf (h) pipe always 2 ahead.
#define ITERL(k, PRE) {                                                         \
    i32x4 bfc = bf[(k) & 1];                                                    \
    acc0 = __builtin_amdgcn_mfma_i32_16x16x64_i8(wv[(k) & 1][0], bfc, acc0, 0, 0, 0); \
    acc1 = __builtin_amdgcn_mfma_i32_16x16x64_i8(wv[(k) & 1][1], bfc, acc1, 0, 0, 0); \
    if (PRE) {                                                                  \
        wv[(k) & 1][0] = *(const i32x4*)(wb + 0 * 4096 + ((k) + 2) * 1024);     \
        wv[(k) & 1][1] = *(const i32x4*)(wb + 1 * 4096 + ((k) + 2) * 1024);     \
    }                                                                           \
    bf[(k) & 1] = *(const i32x4*)(hr + ((k) + 2) * 1024 + lane * 16); }

// Streamed slice iteration: counted wait (8 in flight, oldest 2 done),
// 2 MFMAs, re-issue the same slice for the NEXT step (full-step lead time).
#define ITERV(k, INCSTR, DOLD) {                                                \
    WAIT2(s0[(k) & 3], s1[(k) & 3], 6);                                         \
    i32x4 bfc = bf[(k) & 1];                                                    \
    acc0 = __builtin_amdgcn_mfma_i32_16x16x64_i8(s0[(k) & 3], bfc, acc0, 0, 0, 0); \
    acc1 = __builtin_amdgcn_mfma_i32_16x16x64_i8(s1[(k) & 3], bfc, acc1, 0, 0, 0); \
    if (DOLD) bf[(k) & 1] = *(const i32x4*)(hr + ((k) + 2) * 1024 + lane * 16); \
    LOADW2(s0[(k) & 3], s1[(k) & 3], INCSTR); }

// Drain iteration (last step): counted wait, no re-issue.
#define ITERD(k, N, DOLD) {                                                     \
    WAIT2(s0[(k) & 3], s1[(k) & 3], N);                                         \
    i32x4 bfc = bf[(k) & 1];                                                    \
    acc0 = __builtin_amdgcn_mfma_i32_16x16x64_i8(s0[(k) & 3], bfc, acc0, 0, 0, 0); \
    acc1 = __builtin_amdgcn_mfma_i32_16x16x64_i8(s1[(k) & 3], bfc, acc1, 0, 0, 0); \
    if (DOLD) bf[(k) & 1] = *(const i32x4*)(hr + ((k) + 2) * 1024 + lane * 16); }

// ---- prep 1: per-out-col scales ----
__global__ void pack_scales(const float* __restrict__ Wh,
                            float* __restrict__ invq,    // 127/max
                            float* __restrict__ sclq) {  // max/(127*127)
    int oc   = blockIdx.x;
    int lane = threadIdx.x;
    float m = 0.f;
#pragma unroll
    for (int j = 0; j < 8; ++j) m = fmaxf(m, fabsf(Wh[oc * HIDDEN + lane * 8 + j]));
    for (int d = 1; d < 64; d <<= 1) m = fmaxf(m, __shfl_xor(m, d));
    if (lane == 0) {
        float inv = (m > 0.f) ? 127.0f / m : 0.f;
        invq[oc] = inv;
        sclq[oc] = m / (127.0f * 127.0f);
    }
}

// ---- prep 2: quantize + pack into i8 A-fragment order.
// Frag (tile, kk, lane): 16 int8 of A[oc=tile*16+(lane&15)][k=kk*64+(lane>>4)*16+j]
__global__ void pack_q(const float* __restrict__ Wh,
                       const float* __restrict__ invq,
                       i32x4* __restrict__ Wpk8) {
    int tid  = blockIdx.x * blockDim.x + threadIdx.x;   // 0..16383
    int lane = tid & 63;
    int kk   = (tid >> 6) & 7;
    int mt   = tid >> 9;                                 // global tile 0..31
    int oc   = mt * 16 + (lane & 15);
    int k0   = kk * 64 + (lane >> 4) * 16;
    float inv = invq[oc];
    const float* src = Wh + oc * HIDDEN + k0;
    int w[4];
#pragma unroll
    for (int d = 0; d < 4; ++d) {
        int b0 = __float2int_rn(src[d * 4 + 0] * inv) & 255;
        int b1 = __float2int_rn(src[d * 4 + 1] * inv) & 255;
        int b2 = __float2int_rn(src[d * 4 + 2] * inv) & 255;
        int b3 = __float2int_rn(src[d * 4 + 3] * inv) & 255;
        w[d] = b0 | (b1 << 8) | (b2 << 16) | (b3 << 24);
    }
    i32x4 v = {w[0], w[1], w[2], w[3]};
    Wpk8[(mt * 8 + kk) * 64 + lane] = v;
}

__global__ __launch_bounds__(NTHR)
__attribute__((amdgpu_waves_per_eu(4, 4)))   // cap at 128-VGPR tier (4 waves/EU)
void rnn_main(
    const float* __restrict__ x,      // [1024][256]
    const float* __restrict__ Wx_w,   // [512]
    const float* __restrict__ Wx_b,   // [512]
    const float* __restrict__ Wh_b,   // [512]
    const float* __restrict__ fc_w,   // [24][512]
    const float* __restrict__ fc_b,   // [24]
    const float* __restrict__ sclq,   // [512] dequant scale
    const void*  __restrict__ Wpk8,   // 256 KB packed int8 fragments
    float* __restrict__ out)          // [1024][24]
{
    // LDS: W slices 0..3 resident (128 KB) + int8 h dbuf + bf16 x
    __shared__ __align__(16) char  wlds[4 * 32 * 64 * 16];      // 128 KB
    __shared__ __align__(16) char  hq[2][NKK * 64 * 16];        // 16 KB
    __shared__ __align__(16) unsigned short xsb[TSTEPS * BBLK]; // 8 KB

    const int tid  = threadIdx.x;
    const int lane = tid & 63;
    const int wave = tid >> 6;       // 0..15, owns tiles 2w, 2w+1
    const int bb   = blockIdx.x * BBLK;
    const int arow = lane & 15;      // C/D col = batch row
    const int rowg = lane >> 4;

    // stage x transposed as bf16: xsb[t*16 + r]
    for (int i = tid; i < BBLK * TSTEPS; i += NTHR) {
        int t = i & 255, r = i >> 8;
        xsb[t * 16 + r] = f2bf(x[(bb + r) * TSTEPS + t]);
    }
    // stage W slices 0..3 into LDS: wlds[(mt*4+kk)*64+lane] = Wpk8[(mt*8+kk)*64+lane]
    {
        const i32x4* Wg = (const i32x4*)Wpk8;
        i32x4* WL = (i32x4*)wlds;
        for (int i = tid; i < 8192; i += NTHR) {
            int mt = i >> 8;
            WL[i] = Wg[i + mt * 256];
        }
    }
    // h0 = 0 (both buffers: 16 KB = 1024 vec4)
    {
        i32x4 z = {0, 0, 0, 0};
        ((i32x4*)hq)[tid] = z;
    }

    // per-thread scale/bias tables in registers (24 VGPR), loaded once.
    f32x4 scl_r[2], wx_r[2], bs_r[2];
#pragma unroll
    for (int mtl = 0; mtl < 2; ++mtl) {
        int ocb = wave * 32 + mtl * 16 + rowg * 4;
        scl_r[mtl] = *(const f32x4*)&sclq[ocb];
        wx_r[mtl]  = *(const f32x4*)&Wx_w[ocb];
        f32x4 b1   = *(const f32x4*)&Wx_b[ocb];
        f32x4 b2   = *(const f32x4*)&Wh_b[ocb];
        bs_r[mtl]  = b1 + b2;
    }

    // SRSRC over the 256 KB packed-weight buffer
    uint4v srsrc;
    {
        unsigned long long b = (unsigned long long)Wpk8;
        srsrc[0] = (unsigned int)b;
        srsrc[1] = (unsigned int)(b >> 32);
        srsrc[2] = 256 * 1024;          // num_records bytes
        srsrc[3] = 0x00020000;
    }
    // stream voffsets start at slice 4: byte = tile*8192 + 4*64*16 + lane*16
    unsigned int vo0 = ((wave * 2 + 0) * 512 + 256 + lane) * 16;
    unsigned int vo1 = ((wave * 2 + 1) * 512 + 256 + lane) * 16;

    __syncthreads();   // staging visible; compiler VMEM drained

    // persistent prologue: slices 4..7 for both tile-streams (8 in flight)
    i32x4 s0[4], s1[4];
    LOADW2(s0[0], s1[0], "0x400");       // slice 4
    LOADW2(s0[1], s1[1], "0x400");       // slice 5
    LOADW2(s0[2], s1[2], "0x400");       // slice 6
    LOADW2(s0[3], s1[3], "0xfffff400");  // slice 7, wrap vo->slice 4

    const char* wb = wlds + wave * 8192 + lane * 16;

    // wv pipe prologue for step 0 (slices 0,1 of both tiles)
    i32x4 wv[2][2];
    wv[0][0] = *(const i32x4*)(wb + 0 * 4096 + 0 * 1024);
    wv[0][1] = *(const i32x4*)(wb + 1 * 4096 + 0 * 1024);
    wv[1][0] = *(const i32x4*)(wb + 0 * 4096 + 1 * 1024);
    wv[1][1] = *(const i32x4*)(wb + 1 * 4096 + 1 * 1024);

#pragma clang loop unroll(disable)
    for (int t = 0; t < TSTEPS - 1; ++t) {
        const char* hr = hq[t & 1];
        char*       hw = hq[(t + 1) & 1];

        // h pipe: slices 0,1 (depends on barrier; wv was prefetched pre-barrier)
        i32x4 bf[2];
        bf[0] = *(const i32x4*)(hr + 0 * 1024 + lane * 16);
        bf[1] = *(const i32x4*)(hr + 1 * 1024 + lane * 16);
        const float xv = bf2f(xsb[t * 16 + arow]);
        i32x4 acc0 = {0,0,0,0}, acc1 = {0,0,0,0};

        ITERL(0, 1);
        ITERL(1, 1);
        ITERL(2, 0);
        ITERL(3, 0);
        ITERV(4, "0x400", 1);
        ITERV(5, "0x400", 1);
        ITERV(6, "0x400", 0);
        ITERV(7, "0xfffff400", 0);   // wrap vo back to slice 4 for next step

        // prefetch next step's wv (W-resident, h-independent) BEFORE barrier:
        // LDS latency hides under the epilogue VALU.
        wv[0][0] = *(const i32x4*)(wb + 0 * 4096 + 0 * 1024);
        wv[0][1] = *(const i32x4*)(wb + 1 * 4096 + 0 * 1024);
        wv[1][0] = *(const i32x4*)(wb + 0 * 4096 + 1 * 1024);
        wv[1][1] = *(const i32x4*)(wb + 1 * 4096 + 1 * 1024);

        // epilogue: dequant, tanh (rcp, x127 folded), v_perm byte pack, write.
        // oc = wave*32 + mtl*16 + rowg*4 + r:
        //   slice kk = (2*wave+mtl)>>2, chunk = (2*wave+mtl)&3, byte j0 = rowg*4
        {
            i32x4 accs[2] = {acc0, acc1};
#pragma unroll
            for (int mtl = 0; mtl < 2; ++mtl) {
                int q[4];
#pragma unroll
                for (int r = 0; r < 4; ++r) {
                    float z  = fmaf(xv, wx_r[mtl][r],
                               fmaf((float)accs[mtl][r], scl_r[mtl][r], bs_r[mtl][r]));
                    float e  = __builtin_amdgcn_exp2f(z * LOG2E2);
                    float rc = __builtin_amdgcn_rcpf(e + 1.0f);
                    q[r] = __float2int_rn(fmaf(-254.0f, rc, 127.0f));  // 127*tanh
                }
                unsigned int u =
                    __builtin_amdgcn_perm((unsigned)q[1], (unsigned)q[0], 0x0C0C0400u) |
                    __builtin_amdgcn_perm((unsigned)q[3], (unsigned)q[2], 0x04000C0Cu);
                int tg = 2 * wave + mtl;
                *(unsigned int*)(hw + (tg >> 2) * 1024 + ((tg & 3) * 16 + arow) * 16 + rowg * 4) = u;
            }
        }
        lds_barrier();
    }

    // ---- peeled last step: drain to vmcnt 0, write final h as bf16 ----
    {
        const char* hr = hq[(TSTEPS - 1) & 1];
        i32x4 bf[2];
        bf[0] = *(const i32x4*)(hr + 0 * 1024 + lane * 16);
        bf[1] = *(const i32x4*)(hr + 1 * 1024 + lane * 16);
        const float xv = bf2f(xsb[(TSTEPS - 1) * 16 + arow]);
        i32x4 acc0 = {0,0,0,0}, acc1 = {0,0,0,0};

        ITERL(0, 1);
        ITERL(1, 1);
        ITERL(2, 0);
        ITERL(3, 0);
        ITERD(4, 6, 1);
        ITERD(5, 4, 1);
        ITERD(6, 2, 0);
        ITERD(7, 0, 0);              // vmcnt == 0: stream fully drained

        lds_barrier();               // all reads done before overwrite

        // final h in bf16, plain [b][k] layout over the hq area (16 KB)
        unsigned short* hout = (unsigned short*)hq;
        i32x4 accs[2] = {acc0, acc1};
#pragma unroll
        for (int mtl = 0; mtl < 2; ++mtl) {
            int ocb = wave * 32 + mtl * 16 + rowg * 4;
            us4 pk;
#pragma unroll
            for (int r = 0; r < 4; ++r) {
                float z  = fmaf(xv, wx_r[mtl][r],
                           fmaf((float)accs[mtl][r], scl_r[mtl][r], bs_r[mtl][r]));
                float e  = __builtin_amdgcn_exp2f(z * LOG2E2);
                float rc = __builtin_amdgcn_rcpf(e + 1.0f);
                pk[r] = f2bf(fmaf(-2.0f, rc, 1.0f));
            }
            *(us4*)(hout + (lane & 15) * HIDDEN + ocb) = pk;
        }
        lds_barrier();
    }

    // fc head: 16 x 24 outputs from bf16 h
    if (tid < BBLK * HORIZON) {
        int row = tid / HORIZON;
        int ho  = tid - row * HORIZON;
        float acc = fc_b[ho];
        const float* fw = fc_w + ho * HIDDEN;
        const unsigned short* hf = (const unsigned short*)hq;
#pragma unroll 8
        for (int k = 0; k < HIDDEN; k += 8) {
            ushort8 hv = *(const ushort8*)(hf + row * HIDDEN + k);
#pragma unroll
            for (int j = 0; j < 8; ++j)
                acc += bf2f(hv[j]) * fw[k + j];
        }
        out[(bb + row) * HORIZON + ho] = acc;
    }
}

extern "C" void kernel_launch(void* const* d_in, const int* in_sizes, int n_in,
                              void* d_out, int out_size, void* d_ws, size_t ws_size,
                              hipStream_t stream) {
    const float* x    = (const float*)d_in[0];
    const float* Wx_w = (const float*)d_in[1];
    const float* Wx_b = (const float*)d_in[2];
    const float* Wh_w = (const float*)d_in[3];
    const float* Wh_b = (const float*)d_in[4];
    const float* fc_w = (const float*)d_in[5];
    const float* fc_b = (const float*)d_in[6];
    float* out = (float*)d_out;

    // workspace: [0,256K) int8 fragments; then invq[512], sclq[512]
    i32x4* Wpk8 = (i32x4*)d_ws;
    float* invq = (float*)((char*)d_ws + 256 * 1024);
    float* sclq = invq + HIDDEN;

    hipLaunchKernelGGL(pack_scales, dim3(HIDDEN), dim3(64), 0, stream, Wh_w, invq, sclq);
    hipLaunchKernelGGL(pack_q, dim3(64), dim3(256), 0, stream, Wh_w, invq, Wpk8);
    hipLaunchKernelGGL(rnn_main, dim3(NWG), dim3(NTHR), 0, stream,
                       x, Wx_w, Wx_b, Wh_b, fc_w, fc_b, sclq,
                       (const void*)Wpk8, out);
}

// Round 13
// 303.139 us; speedup vs baseline: 5.0112x; 1.2525x over previous
//
#include <hip/hip_runtime.h>
#include <hip/hip_bf16.h>

#define HIDDEN   512
#define TSTEPS   256
#define HORIZON  24
#define BTOT     1024
#define BBLK     16
#define NWG      (BTOT / BBLK)      // 64 workgroups
#define NTHR     1024               // 16 waves, 2 m-tiles each
#define NKK      8                  // K slices (512 / 64)

typedef __attribute__((ext_vector_type(4))) int            i32x4;
typedef __attribute__((ext_vector_type(4))) float          f32x4;
typedef __attribute__((ext_vector_type(8))) unsigned short ushort8;
typedef __attribute__((ext_vector_type(4))) unsigned short us4;
typedef __attribute__((ext_vector_type(4))) unsigned int   uint4v;

#define LOG2E2 2.8853900817779268f   // 2*log2(e): exp(2z) = exp2(z*LOG2E2)

__device__ __forceinline__ unsigned short f2bf(float f) {
    unsigned int u = __float_as_uint(f);
    u += 0x7FFFu + ((u >> 16) & 1u);   // RNE
    return (unsigned short)(u >> 16);
}
__device__ __forceinline__ float bf2f(unsigned short s) {
    return __uint_as_float(((unsigned int)s) << 16);
}

// LDS-ordering-only barrier.
__device__ __forceinline__ void lds_barrier() {
    asm volatile("s_waitcnt lgkmcnt(0)" ::: "memory");
    __builtin_amdgcn_s_barrier();
    asm volatile("" ::: "memory");
}

// Prologue-only: load one k-slice pair via SRSRC; self-incrementing voffsets.
#define LOADW2(d0, d1)                                               \
    asm volatile("buffer_load_dwordx4 %0, %2, %4, 0 offen\n\t"       \
                 "buffer_load_dwordx4 %1, %3, %4, 0 offen\n\t"       \
                 "v_add_u32 %2, 0x400, %2\n\t"                       \
                 "v_add_u32 %3, 0x400, %3"                           \
                 : "=&v"(d0), "=&v"(d1), "+v"(vo0), "+v"(vo1)        \
                 : "s"(srsrc))

// Register-resident iteration: 2 MFMAs off static weight regs; bf (h) pipe
// kept 2 slices ahead.
#define ITERR(k, DOLD) {                                                        \
    i32x4 bfc = bf[(k) & 1];                                                    \
    acc0 = __builtin_amdgcn_mfma_i32_16x16x64_i8(w0s[k], bfc, acc0, 0, 0, 0);   \
    acc1 = __builtin_amdgcn_mfma_i32_16x16x64_i8(w1s[k], bfc, acc1, 0, 0, 0);   \
    if (DOLD) bf[(k) & 1] = *(const i32x4*)(hr + ((k) + 2) * 1024 + lane * 16); }

// ---- prep 1: per-out-col scales ----
__global__ void pack_scales(const float* __restrict__ Wh,
                            float* __restrict__ invq,    // 127/max
                            float* __restrict__ sclq) {  // max/(127*127)
    int oc   = blockIdx.x;
    int lane = threadIdx.x;
    float m = 0.f;
#pragma unroll
    for (int j = 0; j < 8; ++j) m = fmaxf(m, fabsf(Wh[oc * HIDDEN + lane * 8 + j]));
    for (int d = 1; d < 64; d <<= 1) m = fmaxf(m, __shfl_xor(m, d));
    if (lane == 0) {
        float inv = (m > 0.f) ? 127.0f / m : 0.f;
        invq[oc] = inv;
        sclq[oc] = m / (127.0f * 127.0f);
    }
}

// ---- prep 2: quantize + pack into i8 A-fragment order.
// Frag (tile, kk, lane): 16 int8 of A[oc=tile*16+(lane&15)][k=kk*64+(lane>>4)*16+j]
__global__ void pack_q(const float* __restrict__ Wh,
                       const float* __restrict__ invq,
                       i32x4* __restrict__ Wpk8) {
    int tid  = blockIdx.x * blockDim.x + threadIdx.x;   // 0..16383
    int lane = tid & 63;
    int kk   = (tid >> 6) & 7;
    int mt   = tid >> 9;                                 // global tile 0..31
    int oc   = mt * 16 + (lane & 15);
    int k0   = kk * 64 + (lane >> 4) * 16;
    float inv = invq[oc];
    const float* src = Wh + oc * HIDDEN + k0;
    int w[4];
#pragma unroll
    for (int d = 0; d < 4; ++d) {
        int b0 = __float2int_rn(src[d * 4 + 0] * inv) & 255;
        int b1 = __float2int_rn(src[d * 4 + 1] * inv) & 255;
        int b2 = __float2int_rn(src[d * 4 + 2] * inv) & 255;
        int b3 = __float2int_rn(src[d * 4 + 3] * inv) & 255;
        w[d] = b0 | (b1 << 8) | (b2 << 16) | (b3 << 24);
    }
    i32x4 v = {w[0], w[1], w[2], w[3]};
    Wpk8[(mt * 8 + kk) * 64 + lane] = v;
}

__global__ __launch_bounds__(NTHR)
__attribute__((amdgpu_waves_per_eu(4, 4)))   // 128-VGPR tier (4 waves/EU)
void rnn_main(
    const float* __restrict__ x,      // [1024][256]
    const float* __restrict__ Wx_w,   // [512]
    const float* __restrict__ Wx_b,   // [512]
    const float* __restrict__ Wh_b,   // [512]
    const float* __restrict__ fc_w,   // [24][512]
    const float* __restrict__ fc_b,   // [24]
    const float* __restrict__ sclq,   // [512] dequant scale
    const void*  __restrict__ Wpk8,   // 256 KB packed int8 fragments
    float* __restrict__ out)          // [1024][24]
{
    // LDS: only the int8 h double-buffer + bf16 x staging (24 KB total)
    __shared__ __align__(16) char  hq[2][NKK * 64 * 16];        // 16 KB
    __shared__ __align__(16) unsigned short xsb[TSTEPS * BBLK]; // 8 KB

    const int tid  = threadIdx.x;
    const int lane = tid & 63;
    const int wave = tid >> 6;       // 0..15, owns tiles 2w, 2w+1
    const int bb   = blockIdx.x * BBLK;
    const int arow = lane & 15;      // C/D col = batch row
    const int rowg = lane >> 4;

    // stage x transposed as bf16: xsb[t*16 + r]
    for (int i = tid; i < BBLK * TSTEPS; i += NTHR) {
        int t = i & 255, r = i >> 8;
        xsb[t * 16 + r] = f2bf(x[(bb + r) * TSTEPS + t]);
    }
    // h0 = 0 (both buffers: 16 KB = 1024 vec4)
    {
        i32x4 z = {0, 0, 0, 0};
        ((i32x4*)hq)[tid] = z;
    }

    // per-thread scale/bias tables in registers (24 VGPR), loaded once.
    f32x4 scl_r[2], wx_r[2], bs_r[2];
#pragma unroll
    for (int mtl = 0; mtl < 2; ++mtl) {
        int ocb = wave * 32 + mtl * 16 + rowg * 4;
        scl_r[mtl] = *(const f32x4*)&sclq[ocb];
        wx_r[mtl]  = *(const f32x4*)&Wx_w[ocb];
        f32x4 b1   = *(const f32x4*)&Wx_b[ocb];
        f32x4 b2   = *(const f32x4*)&Wh_b[ocb];
        bs_r[mtl]  = b1 + b2;
    }

    // SRSRC over the 256 KB packed-weight buffer (prologue only)
    uint4v srsrc;
    {
        unsigned long long b = (unsigned long long)Wpk8;
        srsrc[0] = (unsigned int)b;
        srsrc[1] = (unsigned int)(b >> 32);
        srsrc[2] = 256 * 1024;          // num_records bytes
        srsrc[3] = 0x00020000;
    }
    unsigned int vo0 = ((wave * 2 + 0) * 512 + lane) * 16;   // tile 2w,  slice 0
    unsigned int vo1 = ((wave * 2 + 1) * 512 + lane) * 16;   // tile 2w+1, slice 0

    // ---- load ALL 8 slices x 2 tiles into registers (64 VGPRs), ONCE ----
    i32x4 w0s[8], w1s[8];
    LOADW2(w0s[0], w1s[0]);
    LOADW2(w0s[1], w1s[1]);
    LOADW2(w0s[2], w1s[2]);
    LOADW2(w0s[3], w1s[3]);
    LOADW2(w0s[4], w1s[4]);
    LOADW2(w0s[5], w1s[5]);
    LOADW2(w0s[6], w1s[6]);
    LOADW2(w0s[7], w1s[7]);
    // pin: asm-defined after this wait -> cannot be rematerialized or reordered
    asm volatile("s_waitcnt vmcnt(0)"
                 : "+v"(w0s[0]), "+v"(w0s[1]), "+v"(w0s[2]), "+v"(w0s[3]),
                   "+v"(w0s[4]), "+v"(w0s[5]), "+v"(w0s[6]), "+v"(w0s[7]),
                   "+v"(w1s[0]), "+v"(w1s[1]), "+v"(w1s[2]), "+v"(w1s[3]),
                   "+v"(w1s[4]), "+v"(w1s[5]), "+v"(w1s[6]), "+v"(w1s[7])
                 :: "memory");

    __syncthreads();   // staging visible

#pragma clang loop unroll(disable)
    for (int t = 0; t < TSTEPS; ++t) {
        const char* hr = hq[t & 1];
        char*       hw = hq[(t + 1) & 1];

        // h pipe: slices 0,1
        i32x4 bf[2];
        bf[0] = *(const i32x4*)(hr + 0 * 1024 + lane * 16);
        bf[1] = *(const i32x4*)(hr + 1 * 1024 + lane * 16);
        const float xv = bf2f(xsb[t * 16 + arow]);
        i32x4 acc0 = {0,0,0,0}, acc1 = {0,0,0,0};

        ITERR(0, 1);
        ITERR(1, 1);
        ITERR(2, 1);
        ITERR(3, 1);
        ITERR(4, 1);
        ITERR(5, 1);
        ITERR(6, 0);
        ITERR(7, 0);

        if (t < TSTEPS - 1) {
            // epilogue: dequant, tanh (rcp, x127 folded), v_perm pack, write.
            // oc = wave*32 + mtl*16 + rowg*4 + r:
            //   tg = 2*wave+mtl; slice = tg>>2, chunk = tg&3, byte j0 = rowg*4
            i32x4 accs[2] = {acc0, acc1};
#pragma unroll
            for (int mtl = 0; mtl < 2; ++mtl) {
                int q[4];
#pragma unroll
                for (int r = 0; r < 4; ++r) {
                    float z  = fmaf(xv, wx_r[mtl][r],
                               fmaf((float)accs[mtl][r], scl_r[mtl][r], bs_r[mtl][r]));
                    float e  = __builtin_amdgcn_exp2f(z * LOG2E2);
                    float rc = __builtin_amdgcn_rcpf(e + 1.0f);
                    q[r] = __float2int_rn(fmaf(-254.0f, rc, 127.0f));  // 127*tanh
                }
                unsigned int u =
                    __builtin_amdgcn_perm((unsigned)q[1], (unsigned)q[0], 0x0C0C0400u) |
                    __builtin_amdgcn_perm((unsigned)q[3], (unsigned)q[2], 0x04000C0Cu);
                int tg = 2 * wave + mtl;
                *(unsigned int*)(hw + (tg >> 2) * 1024 + ((tg & 3) * 16 + arow) * 16 + rowg * 4) = u;
            }
            lds_barrier();
        } else {
            // last step: final h in bf16, plain [b][k] layout over hq
            lds_barrier();   // all bf reads done before overwrite
            unsigned short* hout = (unsigned short*)hq;
            i32x4 accs[2] = {acc0, acc1};
#pragma unroll
            for (int mtl = 0; mtl < 2; ++mtl) {
                int ocb = wave * 32 + mtl * 16 + rowg * 4;
                us4 pk;
#pragma unroll
                for (int r = 0; r < 4; ++r) {
                    float z  = fmaf(xv, wx_r[mtl][r],
                               fmaf((float)accs[mtl][r], scl_r[mtl][r], bs_r[mtl][r]));
                    float e  = __builtin_amdgcn_exp2f(z * LOG2E2);
                    float rc = __builtin_amdgcn_rcpf(e + 1.0f);
                    pk[r] = f2bf(fmaf(-2.0f, rc, 1.0f));
                }
                *(us4*)(hout + (lane & 15) * HIDDEN + ocb) = pk;
            }
            lds_barrier();
        }
    }

    // fc head: 16 x 24 outputs from bf16 h
    if (tid < BBLK * HORIZON) {
        int row = tid / HORIZON;
        int ho  = tid - row * HORIZON;
        float acc = fc_b[ho];
        const float* fw = fc_w + ho * HIDDEN;
        const unsigned short* hf = (const unsigned short*)hq;
#pragma unroll 8
        for (int k = 0; k < HIDDEN; k += 8) {
            ushort8 hv = *(const ushort8*)(hf + row * HIDDEN + k);
#pragma unroll
            for (int j = 0; j < 8; ++j)
                acc += bf2f(hv[j]) * fw[k + j];
        }
        out[(bb + row) * HORIZON + ho] = acc;
    }
}

extern "C" void kernel_launch(void* const* d_in, const int* in_sizes, int n_in,
                              void* d_out, int out_size, void* d_ws, size_t ws_size,
                              hipStream_t stream) {
    const float* x    = (const float*)d_in[0];
    const float* Wx_w = (const float*)d_in[1];
    const float* Wx_b = (const float*)d_in[2];
    const float* Wh_w = (const float*)d_in[3];
    const float* Wh_b = (const float*)d_in[4];
    const float* fc_w = (const float*)d_in[5];
    const float* fc_b = (const float*)d_in[6];
    float* out = (float*)d_out;

    // workspace: [0,256K) int8 fragments; then invq[512], sclq[512]
    i32x4* Wpk8 = (i32x4*)d_ws;
    float* invq = (float*)((char*)d_ws + 256 * 1024);
    float* sclq = invq + HIDDEN;

    hipLaunchKernelGGL(pack_scales, dim3(HIDDEN), dim3(64), 0, stream, Wh_w, invq, sclq);
    hipLaunchKernelGGL(pack_q, dim3(64), dim3(256), 0, stream, Wh_w, invq, Wpk8);
    hipLaunchKernelGGL(rnn_main, dim3(NWG), dim3(NTHR), 0, stream,
                       x, Wx_w, Wx_b, Wh_b, fc_w, fc_b, sclq,
                       (const void*)Wpk8, out);
}

// Round 14
// 278.337 us; speedup vs baseline: 5.4577x; 1.0891x over previous
//
#include <hip/hip_runtime.h>
#include <hip/hip_bf16.h>

#define HIDDEN   512
#define TSTEPS   256
#define HORIZON  24
#define BTOT     1024
#define BBLK     16
#define NWG      (BTOT / BBLK)      // 64 workgroups
#define NTHR     1024               // 16 waves, 2 m-tiles each
#define NKK      8                  // K slices (512 / 64)

typedef __attribute__((ext_vector_type(4))) int            i32x4;
typedef __attribute__((ext_vector_type(4))) float          f32x4;
typedef __attribute__((ext_vector_type(8))) unsigned short ushort8;
typedef __attribute__((ext_vector_type(4))) unsigned short us4;
typedef __attribute__((ext_vector_type(4))) unsigned int   uint4v;

#define LOG2E2 2.8853900817779268f   // 2*log2(e): exp(2z) = exp2(z*LOG2E2)

__device__ __forceinline__ unsigned short f2bf(float f) {
    unsigned int u = __float_as_uint(f);
    u += 0x7FFFu + ((u >> 16) & 1u);   // RNE
    return (unsigned short)(u >> 16);
}
__device__ __forceinline__ float bf2f(unsigned short s) {
    return __uint_as_float(((unsigned int)s) << 16);
}

// LDS-ordering-only barrier.
__device__ __forceinline__ void lds_barrier() {
    asm volatile("s_waitcnt lgkmcnt(0)" ::: "memory");
    __builtin_amdgcn_s_barrier();
    asm volatile("" ::: "memory");
}

// Prologue-only: load one k-slice pair via SRSRC; self-incrementing voffsets.
#define LOADW2(d0, d1)                                               \
    asm volatile("buffer_load_dwordx4 %0, %2, %4, 0 offen\n\t"       \
                 "buffer_load_dwordx4 %1, %3, %4, 0 offen\n\t"       \
                 "v_add_u32 %2, 0x400, %2\n\t"                       \
                 "v_add_u32 %3, 0x400, %3"                           \
                 : "=&v"(d0), "=&v"(d1), "+v"(vo0), "+v"(vo1)        \
                 : "s"(srsrc))

// Register-resident iteration: 2 MFMAs off static weight regs; bf (h) pipe
// kept 2 slices ahead.
#define ITERR(k, DOLD) {                                                        \
    i32x4 bfc = bfp[(k) & 1];                                                   \
    acc0 = __builtin_amdgcn_mfma_i32_16x16x64_i8(w0s[k], bfc, acc0, 0, 0, 0);   \
    acc1 = __builtin_amdgcn_mfma_i32_16x16x64_i8(w1s[k], bfc, acc1, 0, 0, 0);   \
    if (DOLD) bfp[(k) & 1] = *(const i32x4*)(hr + ((k) + 2) * 1024 + lane * 16); }

// One full RNN step: hr/hw are compile-time buffer pointers (unrolled x2),
// so all LDS addressing reduces to hoisted bases + immediate offsets.
#define STEP(hrp, hwp, tt) {                                                    \
    const char* hr = (hrp);                                                     \
    char*       hw = (hwp);                                                     \
    i32x4 bfp[2];                                                               \
    bfp[0] = *(const i32x4*)(hr + 0 * 1024 + lane * 16);                        \
    bfp[1] = *(const i32x4*)(hr + 1 * 1024 + lane * 16);                        \
    const float xv = bf2f(xsb[(tt) * 16 + arow]);                               \
    i32x4 acc0 = {0,0,0,0}, acc1 = {0,0,0,0};                                   \
    ITERR(0, 1); ITERR(1, 1); ITERR(2, 1); ITERR(3, 1);                         \
    ITERR(4, 1); ITERR(5, 1); ITERR(6, 0); ITERR(7, 0);                         \
    {                                                                           \
        int q0[4], q1[4];                                                       \
        _Pragma("unroll")                                                       \
        for (int r = 0; r < 4; ++r) {                                           \
            float z0 = fmaf(xv, wx_r[0][r],                                     \
                       fmaf((float)acc0[r], scl_r[0][r], bs_r[0][r]));          \
            float e0 = __builtin_amdgcn_exp2f(z0);                              \
            float c0 = __builtin_amdgcn_rcpf(e0 + 1.0f);                        \
            q0[r] = __float2int_rn(fmaf(-254.0f, c0, 127.0f));                  \
            float z1 = fmaf(xv, wx_r[1][r],                                     \
                       fmaf((float)acc1[r], scl_r[1][r], bs_r[1][r]));          \
            float e1 = __builtin_amdgcn_exp2f(z1);                              \
            float c1 = __builtin_amdgcn_rcpf(e1 + 1.0f);                        \
            q1[r] = __float2int_rn(fmaf(-254.0f, c1, 127.0f));                  \
        }                                                                       \
        unsigned int u0 =                                                       \
            __builtin_amdgcn_perm((unsigned)q0[1], (unsigned)q0[0], 0x0C0C0400u) | \
            __builtin_amdgcn_perm((unsigned)q0[3], (unsigned)q0[2], 0x04000C0Cu);  \
        unsigned int u1 =                                                       \
            __builtin_amdgcn_perm((unsigned)q1[1], (unsigned)q1[0], 0x0C0C0400u) | \
            __builtin_amdgcn_perm((unsigned)q1[3], (unsigned)q1[2], 0x04000C0Cu);  \
        *(unsigned int*)(hw + st_off0) = u0;                                    \
        *(unsigned int*)(hw + st_off1) = u1;                                    \
    }                                                                           \
    lds_barrier(); }

// ---- prep 1: per-out-col scales ----
__global__ void pack_scales(const float* __restrict__ Wh,
                            float* __restrict__ invq,    // 127/max
                            float* __restrict__ sclq) {  // max/(127*127)
    int oc   = blockIdx.x;
    int lane = threadIdx.x;
    float m = 0.f;
#pragma unroll
    for (int j = 0; j < 8; ++j) m = fmaxf(m, fabsf(Wh[oc * HIDDEN + lane * 8 + j]));
    for (int d = 1; d < 64; d <<= 1) m = fmaxf(m, __shfl_xor(m, d));
    if (lane == 0) {
        float inv = (m > 0.f) ? 127.0f / m : 0.f;
        invq[oc] = inv;
        sclq[oc] = m / (127.0f * 127.0f);
    }
}

// ---- prep 2: quantize + pack into i8 A-fragment order.
// Frag (tile, kk, lane): 16 int8 of A[oc=tile*16+(lane&15)][k=kk*64+(lane>>4)*16+j]
__global__ void pack_q(const float* __restrict__ Wh,
                       const float* __restrict__ invq,
                       i32x4* __restrict__ Wpk8) {
    int tid  = blockIdx.x * blockDim.x + threadIdx.x;   // 0..16383
    int lane = tid & 63;
    int kk   = (tid >> 6) & 7;
    int mt   = tid >> 9;                                 // global tile 0..31
    int oc   = mt * 16 + (lane & 15);
    int k0   = kk * 64 + (lane >> 4) * 16;
    float inv = invq[oc];
    const float* src = Wh + oc * HIDDEN + k0;
    int w[4];
#pragma unroll
    for (int d = 0; d < 4; ++d) {
        int b0 = __float2int_rn(src[d * 4 + 0] * inv) & 255;
        int b1 = __float2int_rn(src[d * 4 + 1] * inv) & 255;
        int b2 = __float2int_rn(src[d * 4 + 2] * inv) & 255;
        int b3 = __float2int_rn(src[d * 4 + 3] * inv) & 255;
        w[d] = b0 | (b1 << 8) | (b2 << 16) | (b3 << 24);
    }
    i32x4 v = {w[0], w[1], w[2], w[3]};
    Wpk8[(mt * 8 + kk) * 64 + lane] = v;
}

__global__ __launch_bounds__(NTHR)
__attribute__((amdgpu_waves_per_eu(4, 4)))   // 128-VGPR tier (4 waves/EU)
void rnn_main(
    const float* __restrict__ x,      // [1024][256]
    const float* __restrict__ Wx_w,   // [512]
    const float* __restrict__ Wx_b,   // [512]
    const float* __restrict__ Wh_b,   // [512]
    const float* __restrict__ fc_w,   // [24][512]
    const float* __restrict__ fc_b,   // [24]
    const float* __restrict__ sclq,   // [512] dequant scale
    const void*  __restrict__ Wpk8,   // 256 KB packed int8 fragments
    float* __restrict__ out)          // [1024][24]
{
    // LDS: only the int8 h double-buffer + bf16 x staging (24 KB total)
    __shared__ __align__(16) char  hq[2][NKK * 64 * 16];        // 16 KB
    __shared__ __align__(16) unsigned short xsb[TSTEPS * BBLK]; // 8 KB

    const int tid  = threadIdx.x;
    const int lane = tid & 63;
    const int wave = tid >> 6;       // 0..15, owns tiles 2w, 2w+1
    const int bb   = blockIdx.x * BBLK;
    const int arow = lane & 15;      // C/D col = batch row
    const int rowg = lane >> 4;

    // stage x transposed as bf16: xsb[t*16 + r]
    for (int i = tid; i < BBLK * TSTEPS; i += NTHR) {
        int t = i & 255, r = i >> 8;
        xsb[t * 16 + r] = f2bf(x[(bb + r) * TSTEPS + t]);
    }
    // h0 = 0 (both buffers: 16 KB = 1024 vec4)
    {
        i32x4 z = {0, 0, 0, 0};
        ((i32x4*)hq)[tid] = z;
    }

    // per-thread scale/bias tables in registers, with LOG2E2 pre-folded so the
    // epilogue computes e = exp2(z') directly (saves a mul per output).
    f32x4 scl_r[2], wx_r[2], bs_r[2];
#pragma unroll
    for (int mtl = 0; mtl < 2; ++mtl) {
        int ocb = wave * 32 + mtl * 16 + rowg * 4;
        f32x4 s  = *(const f32x4*)&sclq[ocb];
        f32x4 w  = *(const f32x4*)&Wx_w[ocb];
        f32x4 b1 = *(const f32x4*)&Wx_b[ocb];
        f32x4 b2 = *(const f32x4*)&Wh_b[ocb];
#pragma unroll
        for (int r = 0; r < 4; ++r) {
            scl_r[mtl][r] = s[r] * LOG2E2;
            wx_r[mtl][r]  = w[r] * LOG2E2;
            bs_r[mtl][r]  = (b1[r] + b2[r]) * LOG2E2;
        }
    }

    // precomputed epilogue store byte-offsets (thread-constant)
    const int tg0 = 2 * wave, tg1 = 2 * wave + 1;
    const int st_off0 = (tg0 >> 2) * 1024 + ((tg0 & 3) * 16 + arow) * 16 + rowg * 4;
    const int st_off1 = (tg1 >> 2) * 1024 + ((tg1 & 3) * 16 + arow) * 16 + rowg * 4;

    // SRSRC over the 256 KB packed-weight buffer (prologue only)
    uint4v srsrc;
    {
        unsigned long long b = (unsigned long long)Wpk8;
        srsrc[0] = (unsigned int)b;
        srsrc[1] = (unsigned int)(b >> 32);
        srsrc[2] = 256 * 1024;          // num_records bytes
        srsrc[3] = 0x00020000;
    }
    unsigned int vo0 = ((wave * 2 + 0) * 512 + lane) * 16;   // tile 2w,  slice 0
    unsigned int vo1 = ((wave * 2 + 1) * 512 + lane) * 16;   // tile 2w+1, slice 0

    // ---- load ALL 8 slices x 2 tiles into registers (64 VGPRs), ONCE ----
    i32x4 w0s[8], w1s[8];
    LOADW2(w0s[0], w1s[0]);
    LOADW2(w0s[1], w1s[1]);
    LOADW2(w0s[2], w1s[2]);
    LOADW2(w0s[3], w1s[3]);
    LOADW2(w0s[4], w1s[4]);
    LOADW2(w0s[5], w1s[5]);
    LOADW2(w0s[6], w1s[6]);
    LOADW2(w0s[7], w1s[7]);
    // pin: asm-defined after this wait -> cannot be rematerialized or reordered
    asm volatile("s_waitcnt vmcnt(0)"
                 : "+v"(w0s[0]), "+v"(w0s[1]), "+v"(w0s[2]), "+v"(w0s[3]),
                   "+v"(w0s[4]), "+v"(w0s[5]), "+v"(w0s[6]), "+v"(w0s[7]),
                   "+v"(w1s[0]), "+v"(w1s[1]), "+v"(w1s[2]), "+v"(w1s[3]),
                   "+v"(w1s[4]), "+v"(w1s[5]), "+v"(w1s[6]), "+v"(w1s[7])
                 :: "memory");

    __syncthreads();   // staging visible

    // t-loop unrolled x2: buffer pointers are compile-time constants.
    // t = 0..253 (127 pairs), then t = 254 single, then t = 255 final.
#pragma clang loop unroll(disable)
    for (int tp = 0; tp < 127; ++tp) {
        int t0 = 2 * tp;
        STEP(hq[0], hq[1], t0);
        STEP(hq[1], hq[0], t0 + 1);
    }
    STEP(hq[0], hq[1], 254);

    // ---- final step (t = 255): reads hq[1], writes bf16 h over hq area ----
    {
        const char* hr = hq[1];
        i32x4 bfp[2];
        bfp[0] = *(const i32x4*)(hr + 0 * 1024 + lane * 16);
        bfp[1] = *(const i32x4*)(hr + 1 * 1024 + lane * 16);
        const float xv = bf2f(xsb[255 * 16 + arow]);
        i32x4 acc0 = {0,0,0,0}, acc1 = {0,0,0,0};

        ITERR(0, 1); ITERR(1, 1); ITERR(2, 1); ITERR(3, 1);
        ITERR(4, 1); ITERR(5, 1); ITERR(6, 0); ITERR(7, 0);

        lds_barrier();   // all bf reads done before overwrite
        unsigned short* hout = (unsigned short*)hq;
#pragma unroll
        for (int mtl = 0; mtl < 2; ++mtl) {
            int ocb = wave * 32 + mtl * 16 + rowg * 4;
            const i32x4 accv = mtl ? acc1 : acc0;
            us4 pk;
#pragma unroll
            for (int r = 0; r < 4; ++r) {
                float z  = fmaf(xv, wx_r[mtl][r],
                           fmaf((float)accv[r], scl_r[mtl][r], bs_r[mtl][r]));
                float e  = __builtin_amdgcn_exp2f(z);
                float rc = __builtin_amdgcn_rcpf(e + 1.0f);
                pk[r] = f2bf(fmaf(-2.0f, rc, 1.0f));
            }
            *(us4*)(hout + (lane & 15) * HIDDEN + ocb) = pk;
        }
        lds_barrier();
    }

    // fc head: 16 x 24 outputs from bf16 h
    if (tid < BBLK * HORIZON) {
        int row = tid / HORIZON;
        int ho  = tid - row * HORIZON;
        float acc = fc_b[ho];
        const float* fw = fc_w + ho * HIDDEN;
        const unsigned short* hf = (const unsigned short*)hq;
#pragma unroll 8
        for (int k = 0; k < HIDDEN; k += 8) {
            ushort8 hv = *(const ushort8*)(hf + row * HIDDEN + k);
#pragma unroll
            for (int j = 0; j < 8; ++j)
                acc += bf2f(hv[j]) * fw[k + j];
        }
        out[(bb + row) * HORIZON + ho] = acc;
    }
}

extern "C" void kernel_launch(void* const* d_in, const int* in_sizes, int n_in,
                              void* d_out, int out_size, void* d_ws, size_t ws_size,
                              hipStream_t stream) {
    const float* x    = (const float*)d_in[0];
    const float* Wx_w = (const float*)d_in[1];
    const float* Wx_b = (const float*)d_in[2];
    const float* Wh_w = (const float*)d_in[3];
    const float* Wh_b = (const float*)d_in[4];
    const float* fc_w = (const float*)d_in[5];
    const float* fc_b = (const float*)d_in[6];
    float* out = (float*)d_out;

    // workspace: [0,256K) int8 fragments; then invq[512], sclq[512]
    i32x4* Wpk8 = (i32x4*)d_ws;
    float* invq = (float*)((char*)d_ws + 256 * 1024);
    float* sclq = invq + HIDDEN;

    hipLaunchKernelGGL(pack_scales, dim3(HIDDEN), dim3(64), 0, stream, Wh_w, invq, sclq);
    hipLaunchKernelGGL(pack_q, dim3(64), dim3(256), 0, stream, Wh_w, invq, Wpk8);
    hipLaunchKernelGGL(rnn_main, dim3(NWG), dim3(NTHR), 0, stream,
                       x, Wx_w, Wx_b, Wh_b, fc_w, fc_b, sclq,
                       (const void*)Wpk8, out);
}

// Round 15
// 277.205 us; speedup vs baseline: 5.4800x; 1.0041x over previous
//
#include <hip/hip_runtime.h>
#include <hip/hip_bf16.h>

#define HIDDEN   512
#define TSTEPS   256
#define HORIZON  24
#define BTOT     1024
#define BBLK     16
#define NWG      (BTOT / BBLK)      // 64 workgroups
#define NTHR     1024               // 16 waves, 2 m-tiles each
#define NKK      8                  // K slices (512 / 64)

typedef __attribute__((ext_vector_type(4))) int            i32x4;
typedef __attribute__((ext_vector_type(4))) float          f32x4;
typedef __attribute__((ext_vector_type(8))) unsigned short ushort8;
typedef __attribute__((ext_vector_type(4))) unsigned short us4;
typedef __attribute__((ext_vector_type(4))) unsigned int   uint4v;

#define LOG2E2 2.8853900817779268f   // 2*log2(e): exp(2z) = exp2(z*LOG2E2)

__device__ __forceinline__ unsigned short f2bf(float f) {
    unsigned int u = __float_as_uint(f);
    u += 0x7FFFu + ((u >> 16) & 1u);   // RNE
    return (unsigned short)(u >> 16);
}
__device__ __forceinline__ float bf2f(unsigned short s) {
    return __uint_as_float(((unsigned int)s) << 16);
}

// LDS-ordering-only barrier.
__device__ __forceinline__ void lds_barrier() {
    asm volatile("s_waitcnt lgkmcnt(0)" ::: "memory");
    __builtin_amdgcn_s_barrier();
    asm volatile("" ::: "memory");
}

// Prologue-only: load one k-slice pair via SRSRC; self-incrementing voffsets.
#define LOADW2(d0, d1)                                               \
    asm volatile("buffer_load_dwordx4 %0, %2, %4, 0 offen\n\t"       \
                 "buffer_load_dwordx4 %1, %3, %4, 0 offen\n\t"       \
                 "v_add_u32 %2, 0x400, %2\n\t"                       \
                 "v_add_u32 %3, 0x400, %3"                           \
                 : "=&v"(d0), "=&v"(d1), "+v"(vo0), "+v"(vo1)        \
                 : "s"(srsrc))

// Register-resident iteration: 2 MFMAs off static weight regs; bf slice k
// was read at step top (compiler inserts counted lgkmcnt waits).
#define ITERR(k) {                                                              \
    acc0 = __builtin_amdgcn_mfma_i32_16x16x64_i8(w0s[k], bfp[k], acc0, 0, 0, 0); \
    acc1 = __builtin_amdgcn_mfma_i32_16x16x64_i8(w1s[k], bfp[k], acc1, 0, 0, 0); }

// One full RNN step. hr/hw are compile-time buffer pointers (unrolled x2):
// issue all 8 h-slice reads up front (deep LDS pipeline), then 16 MFMAs,
// then the tanh/int8 epilogue.
#define STEP(hrp, hwp, tt) {                                                    \
    const char* hr = (hrp);                                                     \
    char*       hw = (hwp);                                                     \
    i32x4 bfp[8];                                                               \
    _Pragma("unroll")                                                           \
    for (int k = 0; k < 8; ++k)                                                 \
        bfp[k] = *(const i32x4*)(hr + k * 1024 + lane * 16);                    \
    const float xv = bf2f(xsb[(tt) * 16 + arow]);                               \
    i32x4 acc0 = {0,0,0,0}, acc1 = {0,0,0,0};                                   \
    ITERR(0); ITERR(1); ITERR(2); ITERR(3);                                     \
    ITERR(4); ITERR(5); ITERR(6); ITERR(7);                                     \
    {                                                                           \
        int q0[4], q1[4];                                                       \
        _Pragma("unroll")                                                       \
        for (int r = 0; r < 4; ++r) {                                           \
            float z0 = fmaf(xv, wx_r[0][r],                                     \
                       fmaf((float)acc0[r], scl_r[0][r], bs_r[0][r]));          \
            float e0 = __builtin_amdgcn_exp2f(z0);                              \
            float c0 = __builtin_amdgcn_rcpf(e0 + 1.0f);                        \
            q0[r] = __float2int_rn(fmaf(-254.0f, c0, 127.0f));                  \
            float z1 = fmaf(xv, wx_r[1][r],                                     \
                       fmaf((float)acc1[r], scl_r[1][r], bs_r[1][r]));          \
            float e1 = __builtin_amdgcn_exp2f(z1);                              \
            float c1 = __builtin_amdgcn_rcpf(e1 + 1.0f);                        \
            q1[r] = __float2int_rn(fmaf(-254.0f, c1, 127.0f));                  \
        }                                                                       \
        unsigned int u0 =                                                       \
            __builtin_amdgcn_perm((unsigned)q0[1], (unsigned)q0[0], 0x0C0C0400u) | \
            __builtin_amdgcn_perm((unsigned)q0[3], (unsigned)q0[2], 0x04000C0Cu);  \
        unsigned int u1 =                                                       \
            __builtin_amdgcn_perm((unsigned)q1[1], (unsigned)q1[0], 0x0C0C0400u) | \
            __builtin_amdgcn_perm((unsigned)q1[3], (unsigned)q1[2], 0x04000C0Cu);  \
        *(unsigned int*)(hw + st_off0) = u0;                                    \
        *(unsigned int*)(hw + st_off1) = u1;                                    \
    }                                                                           \
    lds_barrier(); }

// ---- prep 1: per-out-col scales ----
__global__ void pack_scales(const float* __restrict__ Wh,
                            float* __restrict__ invq,    // 127/max
                            float* __restrict__ sclq) {  // max/(127*127)
    int oc   = blockIdx.x;
    int lane = threadIdx.x;
    float m = 0.f;
#pragma unroll
    for (int j = 0; j < 8; ++j) m = fmaxf(m, fabsf(Wh[oc * HIDDEN + lane * 8 + j]));
    for (int d = 1; d < 64; d <<= 1) m = fmaxf(m, __shfl_xor(m, d));
    if (lane == 0) {
        float inv = (m > 0.f) ? 127.0f / m : 0.f;
        invq[oc] = inv;
        sclq[oc] = m / (127.0f * 127.0f);
    }
}

// ---- prep 2: quantize + pack into i8 A-fragment order.
// Frag (tile, kk, lane): 16 int8 of A[oc=tile*16+(lane&15)][k=kk*64+(lane>>4)*16+j]
__global__ void pack_q(const float* __restrict__ Wh,
                       const float* __restrict__ invq,
                       i32x4* __restrict__ Wpk8) {
    int tid  = blockIdx.x * blockDim.x + threadIdx.x;   // 0..16383
    int lane = tid & 63;
    int kk   = (tid >> 6) & 7;
    int mt   = tid >> 9;                                 // global tile 0..31
    int oc   = mt * 16 + (lane & 15);
    int k0   = kk * 64 + (lane >> 4) * 16;
    float inv = invq[oc];
    const float* src = Wh + oc * HIDDEN + k0;
    int w[4];
#pragma unroll
    for (int d = 0; d < 4; ++d) {
        int b0 = __float2int_rn(src[d * 4 + 0] * inv) & 255;
        int b1 = __float2int_rn(src[d * 4 + 1] * inv) & 255;
        int b2 = __float2int_rn(src[d * 4 + 2] * inv) & 255;
        int b3 = __float2int_rn(src[d * 4 + 3] * inv) & 255;
        w[d] = b0 | (b1 << 8) | (b2 << 16) | (b3 << 24);
    }
    i32x4 v = {w[0], w[1], w[2], w[3]};
    Wpk8[(mt * 8 + kk) * 64 + lane] = v;
}

__global__ __launch_bounds__(NTHR)
__attribute__((amdgpu_waves_per_eu(4, 4)))   // 128-VGPR tier (4 waves/EU)
void rnn_main(
    const float* __restrict__ x,      // [1024][256]
    const float* __restrict__ Wx_w,   // [512]
    const float* __restrict__ Wx_b,   // [512]
    const float* __restrict__ Wh_b,   // [512]
    const float* __restrict__ fc_w,   // [24][512]
    const float* __restrict__ fc_b,   // [24]
    const float* __restrict__ sclq,   // [512] dequant scale
    const void*  __restrict__ Wpk8,   // 256 KB packed int8 fragments
    float* __restrict__ out)          // [1024][24]
{
    // LDS: only the int8 h double-buffer + bf16 x staging (24 KB total)
    __shared__ __align__(16) char  hq[2][NKK * 64 * 16];        // 16 KB
    __shared__ __align__(16) unsigned short xsb[TSTEPS * BBLK]; // 8 KB

    const int tid  = threadIdx.x;
    const int lane = tid & 63;
    const int wave = tid >> 6;       // 0..15, owns tiles 2w, 2w+1
    const int bb   = blockIdx.x * BBLK;
    const int arow = lane & 15;      // C/D col = batch row
    const int rowg = lane >> 4;

    // stage x transposed as bf16: xsb[t*16 + r]
    for (int i = tid; i < BBLK * TSTEPS; i += NTHR) {
        int t = i & 255, r = i >> 8;
        xsb[t * 16 + r] = f2bf(x[(bb + r) * TSTEPS + t]);
    }
    // h0 = 0 (both buffers: 16 KB = 1024 vec4)
    {
        i32x4 z = {0, 0, 0, 0};
        ((i32x4*)hq)[tid] = z;
    }

    // per-thread scale/bias tables in registers, with LOG2E2 pre-folded so the
    // epilogue computes e = exp2(z') directly.
    f32x4 scl_r[2], wx_r[2], bs_r[2];
#pragma unroll
    for (int mtl = 0; mtl < 2; ++mtl) {
        int ocb = wave * 32 + mtl * 16 + rowg * 4;
        f32x4 s  = *(const f32x4*)&sclq[ocb];
        f32x4 w  = *(const f32x4*)&Wx_w[ocb];
        f32x4 b1 = *(const f32x4*)&Wx_b[ocb];
        f32x4 b2 = *(const f32x4*)&Wh_b[ocb];
#pragma unroll
        for (int r = 0; r < 4; ++r) {
            scl_r[mtl][r] = s[r] * LOG2E2;
            wx_r[mtl][r]  = w[r] * LOG2E2;
            bs_r[mtl][r]  = (b1[r] + b2[r]) * LOG2E2;
        }
    }

    // precomputed epilogue store byte-offsets (thread-constant)
    const int tg0 = 2 * wave, tg1 = 2 * wave + 1;
    const int st_off0 = (tg0 >> 2) * 1024 + ((tg0 & 3) * 16 + arow) * 16 + rowg * 4;
    const int st_off1 = (tg1 >> 2) * 1024 + ((tg1 & 3) * 16 + arow) * 16 + rowg * 4;

    // SRSRC over the 256 KB packed-weight buffer (prologue only)
    uint4v srsrc;
    {
        unsigned long long b = (unsigned long long)Wpk8;
        srsrc[0] = (unsigned int)b;
        srsrc[1] = (unsigned int)(b >> 32);
        srsrc[2] = 256 * 1024;          // num_records bytes
        srsrc[3] = 0x00020000;
    }
    unsigned int vo0 = ((wave * 2 + 0) * 512 + lane) * 16;   // tile 2w,  slice 0
    unsigned int vo1 = ((wave * 2 + 1) * 512 + lane) * 16;   // tile 2w+1, slice 0

    // ---- load ALL 8 slices x 2 tiles into registers (64 VGPRs), ONCE ----
    i32x4 w0s[8], w1s[8];
    LOADW2(w0s[0], w1s[0]);
    LOADW2(w0s[1], w1s[1]);
    LOADW2(w0s[2], w1s[2]);
    LOADW2(w0s[3], w1s[3]);
    LOADW2(w0s[4], w1s[4]);
    LOADW2(w0s[5], w1s[5]);
    LOADW2(w0s[6], w1s[6]);
    LOADW2(w0s[7], w1s[7]);
    // pin: asm-defined after this wait -> cannot be rematerialized or reordered
    asm volatile("s_waitcnt vmcnt(0)"
                 : "+v"(w0s[0]), "+v"(w0s[1]), "+v"(w0s[2]), "+v"(w0s[3]),
                   "+v"(w0s[4]), "+v"(w0s[5]), "+v"(w0s[6]), "+v"(w0s[7]),
                   "+v"(w1s[0]), "+v"(w1s[1]), "+v"(w1s[2]), "+v"(w1s[3]),
                   "+v"(w1s[4]), "+v"(w1s[5]), "+v"(w1s[6]), "+v"(w1s[7])
                 :: "memory");

    __syncthreads();   // staging visible

    // t-loop unrolled x2: buffer pointers are compile-time constants.
    // t = 0..253 (127 pairs), then t = 254 single, then t = 255 final.
#pragma clang loop unroll(disable)
    for (int tp = 0; tp < 127; ++tp) {
        int t0 = 2 * tp;
        STEP(hq[0], hq[1], t0);
        STEP(hq[1], hq[0], t0 + 1);
    }
    STEP(hq[0], hq[1], 254);

    // ---- final step (t = 255): reads hq[1], writes bf16 h over hq area ----
    {
        const char* hr = hq[1];
        i32x4 bfp[8];
#pragma unroll
        for (int k = 0; k < 8; ++k)
            bfp[k] = *(const i32x4*)(hr + k * 1024 + lane * 16);
        const float xv = bf2f(xsb[255 * 16 + arow]);
        i32x4 acc0 = {0,0,0,0}, acc1 = {0,0,0,0};

        ITERR(0); ITERR(1); ITERR(2); ITERR(3);
        ITERR(4); ITERR(5); ITERR(6); ITERR(7);

        lds_barrier();   // all bf reads done before overwrite
        unsigned short* hout = (unsigned short*)hq;
#pragma unroll
        for (int mtl = 0; mtl < 2; ++mtl) {
            int ocb = wave * 32 + mtl * 16 + rowg * 4;
            const i32x4 accv = mtl ? acc1 : acc0;
            us4 pk;
#pragma unroll
            for (int r = 0; r < 4; ++r) {
                float z  = fmaf(xv, wx_r[mtl][r],
                           fmaf((float)accv[r], scl_r[mtl][r], bs_r[mtl][r]));
                float e  = __builtin_amdgcn_exp2f(z);
                float rc = __builtin_amdgcn_rcpf(e + 1.0f);
                pk[r] = f2bf(fmaf(-2.0f, rc, 1.0f));
            }
            *(us4*)(hout + (lane & 15) * HIDDEN + ocb) = pk;
        }
        lds_barrier();
    }

    // fc head: 16 x 24 outputs from bf16 h
    if (tid < BBLK * HORIZON) {
        int row = tid / HORIZON;
        int ho  = tid - row * HORIZON;
        float acc = fc_b[ho];
        const float* fw = fc_w + ho * HIDDEN;
        const unsigned short* hf = (const unsigned short*)hq;
#pragma unroll 8
        for (int k = 0; k < HIDDEN; k += 8) {
            ushort8 hv = *(const ushort8*)(hf + row * HIDDEN + k);
#pragma unroll
            for (int j = 0; j < 8; ++j)
                acc += bf2f(hv[j]) * fw[k + j];
        }
        out[(bb + row) * HORIZON + ho] = acc;
    }
}

extern "C" void kernel_launch(void* const* d_in, const int* in_sizes, int n_in,
                              void* d_out, int out_size, void* d_ws, size_t ws_size,
                              hipStream_t stream) {
    const float* x    = (const float*)d_in[0];
    const float* Wx_w = (const float*)d_in[1];
    const float* Wx_b = (const float*)d_in[2];
    const float* Wh_w = (const float*)d_in[3];
    const float* Wh_b = (const float*)d_in[4];
    const float* fc_w = (const float*)d_in[5];
    const float* fc_b = (const float*)d_in[6];
    float* out = (float*)d_out;

    // workspace: [0,256K) int8 fragments; then invq[512], sclq[512]
    i32x4* Wpk8 = (i32x4*)d_ws;
    float* invq = (float*)((char*)d_ws + 256 * 1024);
    float* sclq = invq + HIDDEN;

    hipLaunchKernelGGL(pack_scales, dim3(HIDDEN), dim3(64), 0, stream, Wh_w, invq, sclq);
    hipLaunchKernelGGL(pack_q, dim3(64), dim3(256), 0, stream, Wh_w, invq, Wpk8);
    hipLaunchKernelGGL(rnn_main, dim3(NWG), dim3(NTHR), 0, stream,
                       x, Wx_w, Wx_b, Wh_b, fc_w, fc_b, sclq,
                       (const void*)Wpk8, out);
}